// Round 2
// baseline (77442.957 us; speedup 1.0000x reference)
//
#include <hip/hip_runtime.h>
#include <cstddef>

// ---------------------------------------------------------------------------
// HOPE block forward, fp32, sliced workspace version.
// B=8, N=8192, DIM=384, HID=1536, 4 chunks, rows/chunk = 16384.
// ---------------------------------------------------------------------------

constexpr float INV_CNT = 1.0f / 6291456.0f;   // 1/(16384*384)

__device__ __forceinline__ float fast_gelu(float x) {
  float u = 0.7978845608028654f * (x + 0.044715f * x * x * x);
  return x / (1.0f + __expf(-2.0f * u));
}
__device__ __forceinline__ float fast_gelu_grad(float x) {
  float x2 = x * x;
  float u = 0.7978845608028654f * (x + 0.044715f * x * x2);
  float s = 1.0f / (1.0f + __expf(-2.0f * u));
  return s + x * s * (1.0f - s) * 1.5957691216057308f * (1.0f + 0.134145f * x2);
}

// ---- LayerNorm: 1 wave per row; y[r] = LN(x[map(r)]) -----------------------
// map(r) = ((r>>shift)*stride) + base + (r & ((1<<shift)-1))
__global__ __launch_bounds__(64)
void ln_kernel(const float* __restrict__ x, const float* __restrict__ g,
               const float* __restrict__ b, float* __restrict__ y,
               int shift, int base, int stride) {
  int r = blockIdx.x;
  int src = ((r >> shift) * stride) + base + (r & ((1 << shift) - 1));
  int lane = threadIdx.x;
  const float* xr = x + (size_t)src * 384;
  float vals[6];
  float s = 0.f, s2 = 0.f;
#pragma unroll
  for (int i = 0; i < 6; ++i) {
    float v = xr[lane + i * 64];
    vals[i] = v; s += v; s2 += v * v;
  }
#pragma unroll
  for (int o = 32; o > 0; o >>= 1) { s += __shfl_xor(s, o); s2 += __shfl_xor(s2, o); }
  float m = s * (1.0f / 384.0f);
  float var = s2 * (1.0f / 384.0f) - m * m;
  float rr = rsqrtf(var + 1e-5f);
  float* yr = y + (size_t)r * 384;
#pragma unroll
  for (int i = 0; i < 6; ++i) {
    int c = lane + i * 64;
    yr[c] = (vals[i] - m) * rr * g[c] + b[c];
  }
}

// ---- GEMM NN: C[map(croff+m)] = A[m] @ B (+bias)(+addsrc) ------------------
template <bool GELU_A>
__global__ __launch_bounds__(256)
void gemm_nn(const float* __restrict__ A, const float* __restrict__ B,
             const float* __restrict__ bias, const float* __restrict__ addsrc,
             float* __restrict__ C, int K, int lda, int ldb, int ldc,
             int croff, int cshift, int cbase, int cstride) {
  __shared__ float As[16][68];
  __shared__ float Bs[16][68];
  const int bm = blockIdx.x * 64, bn = blockIdx.y * 64;
  const int tid = threadIdx.x;
  const int tx = tid & 15, ty = tid >> 4;
  float acc[4][4] = {};
  const float* aptr = A + (size_t)(bm + (tid >> 2)) * lda + ((tid & 3) << 2);
  const float* bptr = B + (size_t)(tid >> 4) * ldb + bn + ((tid & 15) << 2);

  for (int k0 = 0; k0 < K; k0 += 16) {
    float4 av = *(const float4*)(aptr + k0);
    float4 bv = *(const float4*)(bptr + (size_t)k0 * ldb);
    if (GELU_A) {
      av.x = fast_gelu(av.x); av.y = fast_gelu(av.y);
      av.z = fast_gelu(av.z); av.w = fast_gelu(av.w);
    }
    {
      int r = tid >> 2, c = (tid & 3) << 2;
      As[c + 0][r] = av.x; As[c + 1][r] = av.y; As[c + 2][r] = av.z; As[c + 3][r] = av.w;
      int br = tid >> 4, bc = (tid & 15) << 2;
      Bs[br][bc + 0] = bv.x; Bs[br][bc + 1] = bv.y; Bs[br][bc + 2] = bv.z; Bs[br][bc + 3] = bv.w;
    }
    __syncthreads();
#pragma unroll
    for (int kk = 0; kk < 16; ++kk) {
      float a0 = As[kk][ty * 4 + 0], a1 = As[kk][ty * 4 + 1];
      float a2 = As[kk][ty * 4 + 2], a3 = As[kk][ty * 4 + 3];
      float b0 = Bs[kk][tx * 4 + 0], b1 = Bs[kk][tx * 4 + 1];
      float b2 = Bs[kk][tx * 4 + 2], b3 = Bs[kk][tx * 4 + 3];
      acc[0][0] += a0 * b0; acc[0][1] += a0 * b1; acc[0][2] += a0 * b2; acc[0][3] += a0 * b3;
      acc[1][0] += a1 * b0; acc[1][1] += a1 * b1; acc[1][2] += a1 * b2; acc[1][3] += a1 * b3;
      acc[2][0] += a2 * b0; acc[2][1] += a2 * b1; acc[2][2] += a2 * b2; acc[2][3] += a2 * b3;
      acc[3][0] += a3 * b0; acc[3][1] += a3 * b1; acc[3][2] += a3 * b2; acc[3][3] += a3 * b3;
    }
    __syncthreads();
  }
#pragma unroll
  for (int i = 0; i < 4; ++i) {
    int rr = croff + bm + ty * 4 + i;
    int crow = ((rr >> cshift) * cstride) + cbase + (rr & ((1 << cshift) - 1));
    size_t base = (size_t)crow * ldc + bn + tx * 4;
#pragma unroll
    for (int j = 0; j < 4; ++j) {
      float v = acc[i][j];
      if (bias)   v += bias[bn + tx * 4 + j];
      if (addsrc) v += addsrc[base + j];
      C[base + j] = v;
    }
  }
}

// ---- GEMM TN: C[K1,N] += A[M,K1]^T @ B[M,N]  (split-M, atomics) ------------
template <bool GELU_A>
__global__ __launch_bounds__(256)
void gemm_tn(const float* __restrict__ A, const float* __restrict__ B,
             float* __restrict__ C, int ldA, int ldB, int ldc, int mlen) {
  __shared__ float As[16][68];
  __shared__ float Bs[16][68];
  const int bk = blockIdx.x * 64, bn = blockIdx.y * 64;
  const int tid = threadIdx.x;
  const int tx = tid & 15, ty = tid >> 4;
  float acc[4][4] = {};
  const int m0 = blockIdx.z * mlen;
  const float* aptr = A + (size_t)(m0 + (tid >> 4)) * ldA + bk + ((tid & 15) << 2);
  const float* bptr = B + (size_t)(m0 + (tid >> 4)) * ldB + bn + ((tid & 15) << 2);

  for (int mm = 0; mm < mlen; mm += 16) {
    float4 av = *(const float4*)(aptr + (size_t)mm * ldA);
    float4 bv = *(const float4*)(bptr + (size_t)mm * ldB);
    if (GELU_A) {
      av.x = fast_gelu(av.x); av.y = fast_gelu(av.y);
      av.z = fast_gelu(av.z); av.w = fast_gelu(av.w);
    }
    {
      int r = tid >> 4, c = (tid & 15) << 2;
      As[r][c + 0] = av.x; As[r][c + 1] = av.y; As[r][c + 2] = av.z; As[r][c + 3] = av.w;
      Bs[r][c + 0] = bv.x; Bs[r][c + 1] = bv.y; Bs[r][c + 2] = bv.z; Bs[r][c + 3] = bv.w;
    }
    __syncthreads();
#pragma unroll
    for (int kk = 0; kk < 16; ++kk) {
      float a0 = As[kk][ty * 4 + 0], a1 = As[kk][ty * 4 + 1];
      float a2 = As[kk][ty * 4 + 2], a3 = As[kk][ty * 4 + 3];
      float b0 = Bs[kk][tx * 4 + 0], b1 = Bs[kk][tx * 4 + 1];
      float b2 = Bs[kk][tx * 4 + 2], b3 = Bs[kk][tx * 4 + 3];
      acc[0][0] += a0 * b0; acc[0][1] += a0 * b1; acc[0][2] += a0 * b2; acc[0][3] += a0 * b3;
      acc[1][0] += a1 * b0; acc[1][1] += a1 * b1; acc[1][2] += a1 * b2; acc[1][3] += a1 * b3;
      acc[2][0] += a2 * b0; acc[2][1] += a2 * b1; acc[2][2] += a2 * b2; acc[2][3] += a2 * b3;
      acc[3][0] += a3 * b0; acc[3][1] += a3 * b1; acc[3][2] += a3 * b2; acc[3][3] += a3 * b3;
    }
    __syncthreads();
  }
#pragma unroll
  for (int i = 0; i < 4; ++i)
#pragma unroll
    for (int j = 0; j < 4; ++j)
      atomicAdd(&C[(size_t)(bk + ty * 4 + i) * ldc + bn + tx * 4 + j], acc[i][j]);
}

// ---- GEMM NT: C[M,N] = A[M,K] @ B[N,K]^T -----------------------------------
__global__ __launch_bounds__(256)
void gemm_nt(const float* __restrict__ A, const float* __restrict__ B,
             float* __restrict__ C, int K, int lda, int ldb, int ldc) {
  __shared__ float As[16][68];
  __shared__ float Bs[16][68];
  const int bm = blockIdx.x * 64, bn = blockIdx.y * 64;
  const int tid = threadIdx.x;
  const int tx = tid & 15, ty = tid >> 4;
  float acc[4][4] = {};
  const float* aptr = A + (size_t)(bm + (tid >> 2)) * lda + ((tid & 3) << 2);
  const float* bptr = B + (size_t)(bn + (tid >> 2)) * ldb + ((tid & 3) << 2);

  for (int k0 = 0; k0 < K; k0 += 16) {
    float4 av = *(const float4*)(aptr + k0);
    float4 bv = *(const float4*)(bptr + k0);
    {
      int r = tid >> 2, c = (tid & 3) << 2;
      As[c + 0][r] = av.x; As[c + 1][r] = av.y; As[c + 2][r] = av.z; As[c + 3][r] = av.w;
      Bs[c + 0][r] = bv.x; Bs[c + 1][r] = bv.y; Bs[c + 2][r] = bv.z; Bs[c + 3][r] = bv.w;
    }
    __syncthreads();
#pragma unroll
    for (int kk = 0; kk < 16; ++kk) {
      float a0 = As[kk][ty * 4 + 0], a1 = As[kk][ty * 4 + 1];
      float a2 = As[kk][ty * 4 + 2], a3 = As[kk][ty * 4 + 3];
      float b0 = Bs[kk][tx * 4 + 0], b1 = Bs[kk][tx * 4 + 1];
      float b2 = Bs[kk][tx * 4 + 2], b3 = Bs[kk][tx * 4 + 3];
      acc[0][0] += a0 * b0; acc[0][1] += a0 * b1; acc[0][2] += a0 * b2; acc[0][3] += a0 * b3;
      acc[1][0] += a1 * b0; acc[1][1] += a1 * b1; acc[1][2] += a1 * b2; acc[1][3] += a1 * b3;
      acc[2][0] += a2 * b0; acc[2][1] += a2 * b1; acc[2][2] += a2 * b2; acc[2][3] += a2 * b3;
      acc[3][0] += a3 * b0; acc[3][1] += a3 * b1; acc[3][2] += a3 * b2; acc[3][3] += a3 * b3;
    }
    __syncthreads();
  }
#pragma unroll
  for (int i = 0; i < 4; ++i) {
    size_t base = (size_t)(bm + ty * 4 + i) * ldc + bn + tx * 4;
#pragma unroll
    for (int j = 0; j < 4; ++j) C[base + j] = acc[i][j];
  }
}

// ---- RoPE in place on q and k (full chunk: 16384 rows x 16 heads) ----------
__global__ __launch_bounds__(256)
void rope_kernel(float* __restrict__ q, float* __restrict__ k) {
  int idx = blockIdx.x * blockDim.x + threadIdx.x;   // 262144
  int row = idx >> 4;
  int hd = idx & 15;
  int j = row & 2047;
  float pos[3] = { (float)(j >> 8), (float)((j >> 4) & 15), (float)(j & 15) };
  const float freqs[4] = { 1.0f, 0.1f, 0.01f, 0.001f };
  size_t base = (size_t)row * 384 + hd * 24;
  float* ptrs[2] = { q + base, k + base };
#pragma unroll
  for (int m = 0; m < 2; ++m) {
    float* p = ptrs[m];
#pragma unroll
    for (int s = 0; s < 3; ++s) {
#pragma unroll
      for (int pr = 0; pr < 4; ++pr) {
        float ang = pos[s] * freqs[pr];
        float si, co;
        sincosf(ang, &si, &co);
        float e0 = p[s * 8 + 2 * pr], e1 = p[s * 8 + 2 * pr + 1];
        p[s * 8 + 2 * pr]     = e0 * co - e1 * si;
        p[s * 8 + 2 * pr + 1] = e0 * si + e1 * co;
      }
    }
  }
}

// ---- elementwise + reductions ----------------------------------------------
__global__ void do_kernel(float* __restrict__ od, const float* __restrict__ tgt, int n) {
  const float sc = 2.0f * INV_CNT;
  for (int i = blockIdx.x * blockDim.x + threadIdx.x; i < n; i += gridDim.x * blockDim.x)
    od[i] = (od[i] - tgt[i]) * sc;
}

__global__ void dh1_kernel(float* __restrict__ da, const float* __restrict__ h1, int n) {
  for (int i = blockIdx.x * blockDim.x + threadIdx.x; i < n; i += gridDim.x * blockDim.x)
    da[i] *= fast_gelu_grad(h1[i]);
}

__global__ void final_add(float* __restrict__ out, const float* __restrict__ h, int n) {
  for (int i = blockIdx.x * blockDim.x + threadIdx.x; i < n; i += gridDim.x * blockDim.x)
    out[i] += h[i];
}

__global__ __launch_bounds__(256)
void reduce_act(const float* __restrict__ X, float* __restrict__ slot, int n, int mode) {
  float s = 0.f;
  for (int i = blockIdx.x * blockDim.x + threadIdx.x; i < n; i += gridDim.x * blockDim.x) {
    float v = X[i];
    if (mode == 0) s += fmaxf(v, 0.f) + log1pf(__expf(-fabsf(v)));
    else           s += 1.0f / (1.0f + __expf(-v));
  }
  __shared__ float sm[256];
  sm[threadIdx.x] = s; __syncthreads();
  for (int o = 128; o > 0; o >>= 1) {
    if (threadIdx.x < o) sm[threadIdx.x] += sm[threadIdx.x + o];
    __syncthreads();
  }
  if (threadIdx.x == 0) atomicAdd(slot, sm[0]);
}

__global__ __launch_bounds__(128)
void colsum(const float* __restrict__ A, float* __restrict__ out, int ncols, int rpb) {
  int col = blockIdx.x * blockDim.x + threadIdx.x;
  if (col >= ncols) return;
  int r0 = blockIdx.y * rpb;
  float s = 0.f;
  for (int r = r0; r < r0 + rpb; ++r) s += A[(size_t)r * ncols + col];
  atomicAdd(&out[col], s);
}

__global__ __launch_bounds__(256)
void sumsq5(const float* __restrict__ G, float* __restrict__ red, int per_i) {
  int i = blockIdx.y;
  const float* base = G + (size_t)i * per_i;
  float s = 0.f;
  for (int idx = blockIdx.x * blockDim.x + threadIdx.x; idx < per_i; idx += gridDim.x * blockDim.x) {
    float v = base[idx]; s += v * v;
  }
  __shared__ float sm[256];
  sm[threadIdx.x] = s; __syncthreads();
  for (int o = 128; o > 0; o >>= 1) {
    if (threadIdx.x < o) sm[threadIdx.x] += sm[threadIdx.x + o];
    __syncthreads();
  }
  if (threadIdx.x == 0) atomicAdd(&red[2 + i], sm[0]);
}

__global__ __launch_bounds__(256)
void update5(float* __restrict__ S, const float* __restrict__ G,
             const float* __restrict__ red, int per_i) {
  int i = blockIdx.y;
  size_t base = (size_t)i * per_i;
  float em = 0.01f * red[0] * INV_CNT;
  float am = red[1] * INV_CNT;
  float norm = sqrtf(red[2 + i]);
  float sc = fminf(1.0f, 1.0f / (norm + 1e-12f));
  float ws_ = 1.0f - am;
  float gs = em * sc;
  for (int idx = blockIdx.x * blockDim.x + threadIdx.x; idx < per_i; idx += gridDim.x * blockDim.x)
    S[base + idx] = ws_ * S[base + idx] - gs * G[base + idx];
}

// ---------------------------------------------------------------------------
extern "C" void kernel_launch(void* const* d_in, const int* in_sizes, int n_in,
                              void* d_out, int out_size, void* d_ws, size_t ws_size,
                              hipStream_t stream) {
  const float* x    = (const float*)d_in[0];
  const float* n1g  = (const float*)d_in[1];
  const float* n1b  = (const float*)d_in[2];
  const float* qW   = (const float*)d_in[3];
  const float* tW1  = (const float*)d_in[4];
  const float* tb1  = (const float*)d_in[5];
  const float* tW2  = (const float*)d_in[6];
  const float* tb2  = (const float*)d_in[7];
  const float* outW = (const float*)d_in[8];
  const float* outb = (const float*)d_in[9];
  const float* n2g  = (const float*)d_in[10];
  const float* n2b  = (const float*)d_in[11];
  const float* cW1  = (const float*)d_in[12];
  const float* cb1  = (const float*)d_in[13];
  const float* cW2  = (const float*)d_in[14];
  const float* cb2  = (const float*)d_in[15];
  float* out = (float*)d_out;

  const size_t W1SZ = 384 * 1536, W2SZ = 1536 * 384;
  const size_t STATE = 5 * W1SZ + 5 * 1536 + 5 * W2SZ + 5 * 384;  // 5907840
  const size_t FIXED = 2 * STATE + 16 + 4 * (size_t)16384 * 384;   // 36981520

  // choose slice height MS so everything fits in d_ws
  size_t MS = 8192;
  while (MS > 1024 && (FIXED + MS * 3840) * 4 > ws_size) MS >>= 1;
  if ((FIXED + MS * 3840) * 4 > ws_size) {
    // diagnostic fallback: out = x (error signature ~0.3, not ~5.4)
    hipMemcpyAsync(d_out, d_in[0], (size_t)25165824 * 4, hipMemcpyDeviceToDevice, stream);
    return;
  }
  const int NS = (int)(16384 / MS);

  float* ws = (float*)d_ws;
  size_t off = 0;
  auto alloc = [&](size_t n) { float* p = ws + off; off += n; return p; };
  float* SW1 = alloc(5 * W1SZ);
  float* SB1 = alloc(5 * 1536);
  float* SW2 = alloc(5 * W2SZ);
  float* SB2 = alloc(5 * 384);
  float* G1  = alloc(5 * W1SZ);     // G1..G4 contiguous (single memset)
  float* G2  = alloc(5 * 1536);
  float* G3  = alloc(5 * W2SZ);
  float* G4  = alloc(5 * 384);
  float* RED = alloc(16);
  float* Yc  = alloc((size_t)16384 * 384);
  float* Kb  = alloc((size_t)16384 * 384);
  float* Vb  = alloc((size_t)16384 * 384);
  float* Tt  = alloc((size_t)16384 * 384);  // q, then per-memory targets
  float* H1s = alloc(MS * 1536);
  float* DAs = alloc(MS * 1536);
  float* ODs = alloc(MS * 384);
  float* T2s = alloc(MS * 384);

  // init scan state from inputs (every call: determinism)
  hipMemcpyAsync(SW1, tW1, 5 * W1SZ * 4, hipMemcpyDeviceToDevice, stream);
  hipMemcpyAsync(SB1, tb1, 5 * 1536 * 4, hipMemcpyDeviceToDevice, stream);
  hipMemcpyAsync(SW2, tW2, 5 * W2SZ * 4, hipMemcpyDeviceToDevice, stream);
  hipMemcpyAsync(SB2, tb2, 5 * 384 * 4, hipMemcpyDeviceToDevice, stream);

  const size_t grads_bytes = STATE * 4;
  const int gm = (int)(MS / 64);              // gemm grid.x for MS rows
  const int mlen = (MS >= 2048) ? 2048 : (int)MS;
  const int zb = (int)(MS / mlen);
  const int nMS = (int)(MS * 384);

  for (int c = 0; c < 4; ++c) {
    hipMemsetAsync(G1, 0, grads_bytes, stream);
    hipMemsetAsync(RED, 0, 64, stream);

    // LN1, gathered into chunk layout: Yc[r] = LN(x[(r>>11)*8192 + c*2048 + (r&2047)])
    ln_kernel<<<dim3(16384), dim3(64), 0, stream>>>(x, n1g, n1b, Yc, 11, c * 2048, 8192);

    // ---- gen: k, v, eta(mean), alpha(mean) ----
    for (int i = 0; i < 4; ++i) {
      for (int s = 0; s < NS; ++s) {
        const float* Ys = Yc + (size_t)s * MS * 384;
        gemm_nn<false><<<dim3(gm, 24), 256, 0, stream>>>(Ys, SW1 + i * W1SZ,
            SB1 + i * 1536, nullptr, H1s, 384, 384, 1536, 1536, 0, 30, 0, 0);
        float* dst = (i == 0) ? Kb + (size_t)s * MS * 384
                   : (i == 1) ? Vb + (size_t)s * MS * 384 : ODs;
        gemm_nn<true><<<dim3(gm, 6), 256, 0, stream>>>(H1s, SW2 + i * W2SZ,
            SB2 + i * 384, nullptr, dst, 1536, 1536, 384, 384, 0, 30, 0, 0);
        if (i == 2) reduce_act<<<dim3(256), 256, 0, stream>>>(ODs, RED + 0, nMS, 0);
        if (i == 3) reduce_act<<<dim3(256), 256, 0, stream>>>(ODs, RED + 1, nMS, 1);
      }
    }

    // ---- q = yc @ qW (into Tt), rope(q, k) ----
    for (int s = 0; s < NS; ++s)
      gemm_nn<false><<<dim3(gm, 6), 256, 0, stream>>>(Yc + (size_t)s * MS * 384, qW,
          nullptr, nullptr, Tt + (size_t)s * MS * 384, 384, 384, 384, 384, 0, 30, 0, 0);
    rope_kernel<<<dim3(1024), 256, 0, stream>>>(Tt, Kb);

    // ---- out = mlp4(q), projected + scattered: d_out[row] = x[row] + out@outW + outb
    for (int s = 0; s < NS; ++s) {
      gemm_nn<false><<<dim3(gm, 24), 256, 0, stream>>>(Tt + (size_t)s * MS * 384,
          SW1 + 4 * W1SZ, SB1 + 4 * 1536, nullptr, H1s, 384, 384, 1536, 1536, 0, 30, 0, 0);
      gemm_nn<true><<<dim3(gm, 6), 256, 0, stream>>>(H1s, SW2 + 4 * W2SZ,
          SB2 + 4 * 384, nullptr, T2s, 1536, 1536, 384, 384, 0, 30, 0, 0);
      gemm_nn<false><<<dim3(gm, 6), 256, 0, stream>>>(T2s, outW, outb, x, out,
          384, 384, 384, 384, (int)(s * MS), 11, c * 2048, 8192);
    }

    // ---- per-memory: target then grads ----
    for (int i = 0; i < 5; ++i) {
      if (i < 4) {  // target = mlp_i(v) into Tt
        for (int s = 0; s < NS; ++s) {
          gemm_nn<false><<<dim3(gm, 24), 256, 0, stream>>>(Vb + (size_t)s * MS * 384,
              SW1 + i * W1SZ, SB1 + i * 1536, nullptr, H1s, 384, 384, 1536, 1536, 0, 30, 0, 0);
          gemm_nn<true><<<dim3(gm, 6), 256, 0, stream>>>(H1s, SW2 + i * W2SZ,
              SB2 + i * 384, nullptr, Tt + (size_t)s * MS * 384, 1536, 1536, 384, 384, 0, 30, 0, 0);
        }
      }
      for (int s = 0; s < NS; ++s) {
        const float* Ks = Kb + (size_t)s * MS * 384;
        gemm_nn<false><<<dim3(gm, 24), 256, 0, stream>>>(Ks, SW1 + i * W1SZ,
            SB1 + i * 1536, nullptr, H1s, 384, 384, 1536, 1536, 0, 30, 0, 0);
        gemm_nn<true><<<dim3(gm, 6), 256, 0, stream>>>(H1s, SW2 + i * W2SZ,
            SB2 + i * 384, nullptr, ODs, 1536, 1536, 384, 384, 0, 30, 0, 0);
        const float* tg = ((i < 4) ? Tt : Vb) + (size_t)s * MS * 384;
        do_kernel<<<dim3(256), 256, 0, stream>>>(ODs, tg, nMS);
        colsum<<<dim3(3, (int)(MS / 256)), 128, 0, stream>>>(ODs, G4 + i * 384, 384, 256);
        gemm_tn<true><<<dim3(24, 6, zb), 256, 0, stream>>>(H1s, ODs, G3 + i * W2SZ,
            1536, 384, 384, mlen);
        gemm_nt<<<dim3(gm, 24), 256, 0, stream>>>(ODs, SW2 + i * W2SZ, DAs, 384, 384, 384, 1536);
        dh1_kernel<<<dim3(512), 256, 0, stream>>>(DAs, H1s, (int)(MS * 1536));
        colsum<<<dim3(12, (int)(MS / 256)), 128, 0, stream>>>(DAs, G2 + i * 1536, 1536, 256);
        gemm_tn<false><<<dim3(6, 24, zb), 256, 0, stream>>>(Ks, DAs, G1 + i * W1SZ,
            384, 1536, 1536, mlen);
      }
    }

    // ---- norms + state update ----
    sumsq5<<<dim3(256, 5), 256, 0, stream>>>(G1, RED, (int)W1SZ);
    sumsq5<<<dim3(2, 5), 256, 0, stream>>>(G2, RED, 1536);
    sumsq5<<<dim3(256, 5), 256, 0, stream>>>(G3, RED, (int)W2SZ);
    sumsq5<<<dim3(2, 5), 256, 0, stream>>>(G4, RED, 384);
    update5<<<dim3(512, 5), 256, 0, stream>>>(SW1, G1, RED, (int)W1SZ);
    update5<<<dim3(4, 5), 256, 0, stream>>>(SB1, G2, RED, 1536);
    update5<<<dim3(512, 5), 256, 0, stream>>>(SW2, G3, RED, (int)W2SZ);
    update5<<<dim3(4, 5), 256, 0, stream>>>(SB2, G4, RED, 384);
  }

  // ---- norm2 + 3 CMS MLP layers + final residual, per MS-row slice ----
  const int NCS = (int)(65536 / MS);
  for (int s = 0; s < NCS; ++s) {
    float* hc = ODs; float* hn = T2s;
    ln_kernel<<<dim3((int)MS), dim3(64), 0, stream>>>(out, n2g, n2b, hc, 30, (int)(s * MS), 0);
    for (int l = 0; l < 3; ++l) {
      gemm_nn<false><<<dim3(gm, 24), 256, 0, stream>>>(hc, cW1 + (size_t)l * W1SZ,
          cb1 + l * 1536, nullptr, H1s, 384, 384, 1536, 1536, 0, 30, 0, 0);
      gemm_nn<true><<<dim3(gm, 6), 256, 0, stream>>>(H1s, cW2 + (size_t)l * W2SZ,
          cb2 + l * 384, nullptr, hn, 1536, 1536, 384, 384, 0, 30, 0, 0);
      float* t = hc; hc = hn; hn = t;
    }
    final_add<<<dim3(512), 256, 0, stream>>>(out + (size_t)s * MS * 384, hc, nMS);
  }
}

// Round 3
// 34060.977 us; speedup vs baseline: 2.2737x; 2.2737x over previous
//
#include <hip/hip_runtime.h>
#include <cstddef>

// ---------------------------------------------------------------------------
// HOPE block forward. bf16-MFMA GEMMs, fp32 everything else.
// B=8, N=8192, DIM=384, HID=1536, 4 chunks, rows/chunk = 16384.
// ---------------------------------------------------------------------------

typedef __bf16 bf16;
typedef __bf16 bf16x4 __attribute__((ext_vector_type(4)));
typedef __bf16 bf16x8 __attribute__((ext_vector_type(8)));
typedef float  f32x4  __attribute__((ext_vector_type(4)));

constexpr float INV_CNT = 1.0f / 6291456.0f;   // 1/(16384*384)

__device__ __forceinline__ float fast_gelu(float x) {
  float u = 0.7978845608028654f * (x + 0.044715f * x * x * x);
  return x / (1.0f + __expf(-2.0f * u));
}
__device__ __forceinline__ float fast_gelu_grad(float x) {
  float x2 = x * x;
  float u = 0.7978845608028654f * (x + 0.044715f * x * x2);
  float s = 1.0f / (1.0f + __expf(-2.0f * u));
  return s + x * s * (1.0f - s) * 1.5957691216057308f * (1.0f + 0.134145f * x2);
}
__device__ __forceinline__ f32x4 gelu4(f32x4 v) {
  v[0] = fast_gelu(v[0]); v[1] = fast_gelu(v[1]);
  v[2] = fast_gelu(v[2]); v[3] = fast_gelu(v[3]);
  return v;
}

// ---- LayerNorm: 1 wave per row; y[r] = LN(x[map(r)]) -----------------------
__global__ __launch_bounds__(64)
void ln_kernel(const float* __restrict__ x, const float* __restrict__ g,
               const float* __restrict__ b, float* __restrict__ y,
               int shift, int base, int stride) {
  int r = blockIdx.x;
  int src = ((r >> shift) * stride) + base + (r & ((1 << shift) - 1));
  int lane = threadIdx.x;
  const float* xr = x + (size_t)src * 384;
  float vals[6];
  float s = 0.f, s2 = 0.f;
#pragma unroll
  for (int i = 0; i < 6; ++i) {
    float v = xr[lane + i * 64];
    vals[i] = v; s += v; s2 += v * v;
  }
#pragma unroll
  for (int o = 32; o > 0; o >>= 1) { s += __shfl_xor(s, o); s2 += __shfl_xor(s2, o); }
  float m = s * (1.0f / 384.0f);
  float var = s2 * (1.0f / 384.0f) - m * m;
  float rr = rsqrtf(var + 1e-5f);
  float* yr = y + (size_t)r * 384;
#pragma unroll
  for (int i = 0; i < 6; ++i) {
    int c = lane + i * 64;
    yr[c] = (vals[i] - m) * rr * g[c] + b[c];
  }
}

// ---- weight prep: transpose fp32 [R][C] -> bf16 [C][R] ---------------------
__global__ __launch_bounds__(256)
void trans_w(const float* __restrict__ in, bf16* __restrict__ out, int R, int C) {
  __shared__ float t[32][33];
  int c0 = blockIdx.x * 32, r0 = blockIdx.y * 32;
  int tr = threadIdx.x >> 3, tc = (threadIdx.x & 7) * 4;
  f32x4 v = *(const f32x4*)&in[(size_t)(r0 + tr) * C + c0 + tc];
  t[tr][tc + 0] = v[0]; t[tr][tc + 1] = v[1]; t[tr][tc + 2] = v[2]; t[tr][tc + 3] = v[3];
  __syncthreads();
  bf16x4 o;
  o[0] = (bf16)t[tc + 0][tr]; o[1] = (bf16)t[tc + 1][tr];
  o[2] = (bf16)t[tc + 2][tr]; o[3] = (bf16)t[tc + 3][tr];
  *(bf16x4*)&out[(size_t)(c0 + tr) * R + r0 + tc] = o;
}

// ---- weight prep: straight fp32 -> bf16 copy -------------------------------
__global__ __launch_bounds__(256)
void copy_bf16(const float* __restrict__ in, bf16* __restrict__ out, int n) {
  int i = (blockIdx.x * 256 + threadIdx.x) * 4;
  if (i < n) {
    f32x4 v = *(const f32x4*)&in[i];
    bf16x4 o; o[0] = (bf16)v[0]; o[1] = (bf16)v[1]; o[2] = (bf16)v[2]; o[3] = (bf16)v[3];
    *(bf16x4*)&out[i] = o;
  }
}

// ---- MFMA GEMM fwd: C[map(croff+m)][i] = sum_k act(Act[m][k]) * W[i][k] ----
// Act fp32 [M][K] (row stride K), W bf16 [Itot][K], C fp32 (ldc).
// +bias[i], +addsrc (indexed like C), optional gelu on Act load.
template <bool GELU_ACT>
__global__ __launch_bounds__(256)
void mm_fwd(const float* __restrict__ Act, const bf16* __restrict__ W,
            const float* __restrict__ bias, const float* __restrict__ addsrc,
            float* __restrict__ C, int K, int ldc,
            int croff, int cshift, int cbase, int cstride) {
  __shared__ bf16 sW[128][40];
  __shared__ bf16 sA[128][40];
  __shared__ float sT[4][16][68];
  const int tid = threadIdx.x;
  const int m0 = blockIdx.x * 128, i0 = blockIdx.y * 128;
  const int sm = tid >> 1, sk = (tid & 1) << 4;
  const float* ap = Act + (size_t)(m0 + sm) * K + sk;
  const bf16*  wp = W   + (size_t)(i0 + sm) * K + sk;
  const int l = tid & 63, w = tid >> 6;
  const int a = l & 15, g = l >> 4;
  const int wi0 = (w & 1) * 64, wm0 = (w >> 1) * 64;

  f32x4 acc[4][4];
#pragma unroll
  for (int i = 0; i < 4; ++i)
#pragma unroll
    for (int j = 0; j < 4; ++j) acc[i][j] = f32x4{0.f, 0.f, 0.f, 0.f};

  for (int k0 = 0; k0 < K; k0 += 32) {
    *(bf16x8*)&sW[sm][sk]     = *(const bf16x8*)(wp + k0);
    *(bf16x8*)&sW[sm][sk + 8] = *(const bf16x8*)(wp + k0 + 8);
    f32x4 v0 = *(const f32x4*)(ap + k0);
    f32x4 v1 = *(const f32x4*)(ap + k0 + 4);
    f32x4 v2 = *(const f32x4*)(ap + k0 + 8);
    f32x4 v3 = *(const f32x4*)(ap + k0 + 12);
    if (GELU_ACT) { v0 = gelu4(v0); v1 = gelu4(v1); v2 = gelu4(v2); v3 = gelu4(v3); }
    bf16x8 h0, h1;
    h0[0] = (bf16)v0[0]; h0[1] = (bf16)v0[1]; h0[2] = (bf16)v0[2]; h0[3] = (bf16)v0[3];
    h0[4] = (bf16)v1[0]; h0[5] = (bf16)v1[1]; h0[6] = (bf16)v1[2]; h0[7] = (bf16)v1[3];
    h1[0] = (bf16)v2[0]; h1[1] = (bf16)v2[1]; h1[2] = (bf16)v2[2]; h1[3] = (bf16)v2[3];
    h1[4] = (bf16)v3[0]; h1[5] = (bf16)v3[1]; h1[6] = (bf16)v3[2]; h1[7] = (bf16)v3[3];
    *(bf16x8*)&sA[sm][sk]     = h0;
    *(bf16x8*)&sA[sm][sk + 8] = h1;
    __syncthreads();
    bf16x8 Af[4], Bf[4];
#pragma unroll
    for (int f = 0; f < 4; ++f) {
      Af[f] = *(const bf16x8*)&sW[wi0 + f * 16 + a][g * 8];
      Bf[f] = *(const bf16x8*)&sA[wm0 + f * 16 + a][g * 8];
    }
#pragma unroll
    for (int fi = 0; fi < 4; ++fi)
#pragma unroll
      for (int fm = 0; fm < 4; ++fm)
        acc[fi][fm] = __builtin_amdgcn_mfma_f32_16x16x32_bf16(Af[fi], Bf[fm], acc[fi][fm], 0, 0, 0);
    __syncthreads();
  }

  // epilogue: LDS transpose -> coalesced row-major stores with fused ops
  float* T = &sT[w][0][0];
  const int iB = i0 + wi0;
  f32x4 b4 = f32x4{0.f, 0.f, 0.f, 0.f};
  if (bias) b4 = *(const f32x4*)&bias[iB + a * 4];
#pragma unroll
  for (int fm = 0; fm < 4; ++fm) {
#pragma unroll
    for (int fi = 0; fi < 4; ++fi)
      *(f32x4*)&T[a * 68 + fi * 16 + g * 4] = acc[fi][fm];
    asm volatile("s_waitcnt lgkmcnt(0)" ::: "memory");
#pragma unroll
    for (int q = 0; q < 4; ++q) {
      int ml = wm0 + fm * 16 + q * 4 + g;
      int rr = croff + m0 + ml;
      int crow = ((rr >> cshift) * cstride) + cbase + (rr & ((1 << cshift) - 1));
      size_t cb = (size_t)crow * ldc + iB + a * 4;
      f32x4 v = *(const f32x4*)&T[(q * 4 + g) * 68 + a * 4];
      v += b4;
      if (addsrc) v += *(const f32x4*)&addsrc[cb];
      *(f32x4*)&C[cb] = v;
    }
  }
}

// ---- MFMA GEMM TN: G[i1][i2] += sum_m act(A[m][i1]) * B[m][i2] -------------
// A fp32 [M][lda], B fp32 [M][ldb], G fp32 [lda? no: I1tot][ldb], atomics.
template <bool GELU_A>
__global__ __launch_bounds__(256)
void mm_tn(const float* __restrict__ A, const float* __restrict__ B,
           float* __restrict__ G, int lda, int ldb, int mlen) {
  __shared__ bf16 s1[128][40];
  __shared__ bf16 s2[128][40];
  const int tid = threadIdx.x;
  const int i1o = blockIdx.x * 128, i2o = blockIdx.y * 128;
  const int mb = blockIdx.z * mlen;
  const int iq = (tid & 31) * 4, mq = (tid >> 5) * 4;
  const int l = tid & 63, w = tid >> 6;
  const int a = l & 15, g = l >> 4;
  const int w1 = (w & 1) * 64, w2 = (w >> 1) * 64;

  f32x4 acc[4][4];
#pragma unroll
  for (int i = 0; i < 4; ++i)
#pragma unroll
    for (int j = 0; j < 4; ++j) acc[i][j] = f32x4{0.f, 0.f, 0.f, 0.f};

  for (int m0 = 0; m0 < mlen; m0 += 32) {
    {
      const float* p = A + (size_t)(mb + m0 + mq) * lda + i1o + iq;
      f32x4 r0 = *(const f32x4*)(p);
      f32x4 r1 = *(const f32x4*)(p + lda);
      f32x4 r2 = *(const f32x4*)(p + 2 * (size_t)lda);
      f32x4 r3 = *(const f32x4*)(p + 3 * (size_t)lda);
      if (GELU_A) { r0 = gelu4(r0); r1 = gelu4(r1); r2 = gelu4(r2); r3 = gelu4(r3); }
#pragma unroll
      for (int c2 = 0; c2 < 4; ++c2) {
        bf16x4 o;
        o[0] = (bf16)r0[c2]; o[1] = (bf16)r1[c2]; o[2] = (bf16)r2[c2]; o[3] = (bf16)r3[c2];
        *(bf16x4*)&s1[iq + c2][mq] = o;
      }
    }
    {
      const float* p = B + (size_t)(mb + m0 + mq) * ldb + i2o + iq;
      f32x4 r0 = *(const f32x4*)(p);
      f32x4 r1 = *(const f32x4*)(p + ldb);
      f32x4 r2 = *(const f32x4*)(p + 2 * (size_t)ldb);
      f32x4 r3 = *(const f32x4*)(p + 3 * (size_t)ldb);
#pragma unroll
      for (int c2 = 0; c2 < 4; ++c2) {
        bf16x4 o;
        o[0] = (bf16)r0[c2]; o[1] = (bf16)r1[c2]; o[2] = (bf16)r2[c2]; o[3] = (bf16)r3[c2];
        *(bf16x4*)&s2[iq + c2][mq] = o;
      }
    }
    __syncthreads();
    bf16x8 Af[4], Bf[4];
#pragma unroll
    for (int f = 0; f < 4; ++f) {
      Af[f] = *(const bf16x8*)&s1[w1 + f * 16 + a][g * 8];
      Bf[f] = *(const bf16x8*)&s2[w2 + f * 16 + a][g * 8];
    }
#pragma unroll
    for (int f1 = 0; f1 < 4; ++f1)
#pragma unroll
      for (int f2 = 0; f2 < 4; ++f2)
        acc[f1][f2] = __builtin_amdgcn_mfma_f32_16x16x32_bf16(Af[f1], Bf[f2], acc[f1][f2], 0, 0, 0);
    __syncthreads();
  }
#pragma unroll
  for (int f1 = 0; f1 < 4; ++f1)
#pragma unroll
    for (int f2 = 0; f2 < 4; ++f2)
#pragma unroll
      for (int r = 0; r < 4; ++r)
        atomicAdd(&G[(size_t)(i1o + w1 + f1 * 16 + g * 4 + r) * ldb + i2o + w2 + f2 * 16 + a],
                  acc[f1][f2][r]);
}

// ---- RoPE in place on q and k (full chunk) ---------------------------------
__global__ __launch_bounds__(256)
void rope_kernel(float* __restrict__ q, float* __restrict__ k) {
  int idx = blockIdx.x * blockDim.x + threadIdx.x;   // 262144
  int row = idx >> 4;
  int hd = idx & 15;
  int j = row & 2047;
  float pos[3] = { (float)(j >> 8), (float)((j >> 4) & 15), (float)(j & 15) };
  const float freqs[4] = { 1.0f, 0.1f, 0.01f, 0.001f };
  size_t base = (size_t)row * 384 + hd * 24;
  float* ptrs[2] = { q + base, k + base };
#pragma unroll
  for (int m = 0; m < 2; ++m) {
    float* p = ptrs[m];
#pragma unroll
    for (int s = 0; s < 3; ++s) {
#pragma unroll
      for (int pr = 0; pr < 4; ++pr) {
        float ang = pos[s] * freqs[pr];
        float si, co;
        sincosf(ang, &si, &co);
        float e0 = p[s * 8 + 2 * pr], e1 = p[s * 8 + 2 * pr + 1];
        p[s * 8 + 2 * pr]     = e0 * co - e1 * si;
        p[s * 8 + 2 * pr + 1] = e0 * si + e1 * co;
      }
    }
  }
}

// ---- elementwise + reductions ----------------------------------------------
__global__ void do_kernel(float* __restrict__ od, const float* __restrict__ tgt, int n) {
  const float sc = 2.0f * INV_CNT;
  for (int i = blockIdx.x * blockDim.x + threadIdx.x; i < n; i += gridDim.x * blockDim.x)
    od[i] = (od[i] - tgt[i]) * sc;
}

__global__ void dh1_kernel(float* __restrict__ da, const float* __restrict__ h1, int n) {
  for (int i = blockIdx.x * blockDim.x + threadIdx.x; i < n; i += gridDim.x * blockDim.x)
    da[i] *= fast_gelu_grad(h1[i]);
}

__global__ void final_add(float* __restrict__ out, const float* __restrict__ h, int n) {
  for (int i = blockIdx.x * blockDim.x + threadIdx.x; i < n; i += gridDim.x * blockDim.x)
    out[i] += h[i];
}

__global__ __launch_bounds__(256)
void reduce_act(const float* __restrict__ X, float* __restrict__ slot, int n, int mode) {
  float s = 0.f;
  for (int i = blockIdx.x * blockDim.x + threadIdx.x; i < n; i += gridDim.x * blockDim.x) {
    float v = X[i];
    if (mode == 0) s += fmaxf(v, 0.f) + log1pf(__expf(-fabsf(v)));
    else           s += 1.0f / (1.0f + __expf(-v));
  }
  __shared__ float sm[256];
  sm[threadIdx.x] = s; __syncthreads();
  for (int o = 128; o > 0; o >>= 1) {
    if (threadIdx.x < o) sm[threadIdx.x] += sm[threadIdx.x + o];
    __syncthreads();
  }
  if (threadIdx.x == 0) atomicAdd(slot, sm[0]);
}

__global__ __launch_bounds__(128)
void colsum(const float* __restrict__ A, float* __restrict__ out, int ncols, int rpb) {
  int col = blockIdx.x * blockDim.x + threadIdx.x;
  if (col >= ncols) return;
  int r0 = blockIdx.y * rpb;
  float s = 0.f;
  for (int r = r0; r < r0 + rpb; ++r) s += A[(size_t)r * ncols + col];
  atomicAdd(&out[col], s);
}

__global__ __launch_bounds__(256)
void sumsq5(const float* __restrict__ G, float* __restrict__ red, int per_i) {
  int i = blockIdx.y;
  const float* base = G + (size_t)i * per_i;
  float s = 0.f;
  for (int idx = blockIdx.x * blockDim.x + threadIdx.x; idx < per_i; idx += gridDim.x * blockDim.x) {
    float v = base[idx]; s += v * v;
  }
  __shared__ float sm[256];
  sm[threadIdx.x] = s; __syncthreads();
  for (int o = 128; o > 0; o >>= 1) {
    if (threadIdx.x < o) sm[threadIdx.x] += sm[threadIdx.x + o];
    __syncthreads();
  }
  if (threadIdx.x == 0) atomicAdd(&red[2 + i], sm[0]);
}

__global__ __launch_bounds__(256)
void update5(float* __restrict__ S, const float* __restrict__ G,
             const float* __restrict__ red, int per_i) {
  int i = blockIdx.y;
  size_t base = (size_t)i * per_i;
  float em = 0.01f * red[0] * INV_CNT;
  float am = red[1] * INV_CNT;
  float norm = sqrtf(red[2 + i]);
  float sc = fminf(1.0f, 1.0f / (norm + 1e-12f));
  float ws_ = 1.0f - am;
  float gs = em * sc;
  for (int idx = blockIdx.x * blockDim.x + threadIdx.x; idx < per_i; idx += gridDim.x * blockDim.x)
    S[base + idx] = ws_ * S[base + idx] - gs * G[base + idx];
}

// ---------------------------------------------------------------------------
extern "C" void kernel_launch(void* const* d_in, const int* in_sizes, int n_in,
                              void* d_out, int out_size, void* d_ws, size_t ws_size,
                              hipStream_t stream) {
  const float* x    = (const float*)d_in[0];
  const float* n1g  = (const float*)d_in[1];
  const float* n1b  = (const float*)d_in[2];
  const float* qW   = (const float*)d_in[3];
  const float* tW1  = (const float*)d_in[4];
  const float* tb1  = (const float*)d_in[5];
  const float* tW2  = (const float*)d_in[6];
  const float* tb2  = (const float*)d_in[7];
  const float* outW = (const float*)d_in[8];
  const float* outb = (const float*)d_in[9];
  const float* n2g  = (const float*)d_in[10];
  const float* n2b  = (const float*)d_in[11];
  const float* cW1  = (const float*)d_in[12];
  const float* cb1  = (const float*)d_in[13];
  const float* cW2  = (const float*)d_in[14];
  const float* cb2  = (const float*)d_in[15];
  float* out = (float*)d_out;

  const size_t W1SZ = 384 * 1536, W2SZ = 1536 * 384;
  const size_t STATE = 5 * W1SZ + 5 * 1536 + 5 * W2SZ + 5 * 384;
  // bf16 buffers (element counts), stored in f32 slots (n/2 each)
  const size_t BF_ELEMS = 15 * W1SZ + 2 * 147456 + 6 * W1SZ;  // sw1t+sw2t+sw2c+qwt+owt+cms
  const size_t FIXED = 2 * STATE + 16 + 4 * (size_t)16384 * 384 + BF_ELEMS / 2;

  size_t MS = 8192;
  while (MS > 512 && (FIXED + MS * 3840) * 4 > ws_size) MS >>= 1;
  if ((FIXED + MS * 3840) * 4 > ws_size) {
    hipMemcpyAsync(d_out, d_in[0], (size_t)25165824 * 4, hipMemcpyDeviceToDevice, stream);
    return;
  }
  const int NS = (int)(16384 / MS);

  float* ws = (float*)d_ws;
  size_t off = 0;
  auto alloc = [&](size_t n) { float* p = ws + off; off += n; return p; };
  float* SW1 = alloc(5 * W1SZ);
  float* SB1 = alloc(5 * 1536);
  float* SW2 = alloc(5 * W2SZ);
  float* SB2 = alloc(5 * 384);
  float* G1  = alloc(5 * W1SZ);     // G1..G4 contiguous (single memset)
  float* G2  = alloc(5 * 1536);
  float* G3  = alloc(5 * W2SZ);
  float* G4  = alloc(5 * 384);
  float* RED = alloc(16);
  float* Yc  = alloc((size_t)16384 * 384);
  float* Kb  = alloc((size_t)16384 * 384);
  float* Vb  = alloc((size_t)16384 * 384);
  float* Tt  = alloc((size_t)16384 * 384);  // q, then per-memory targets
  bf16* sw1t = (bf16*)alloc(5 * W1SZ / 2);  // [1536][384] x5
  bf16* sw2t = (bf16*)alloc(5 * W2SZ / 2);  // [384][1536] x5
  bf16* sw2c = (bf16*)alloc(5 * W2SZ / 2);  // [1536][384] x5 (straight copy)
  bf16* qwt  = (bf16*)alloc(147456 / 2);    // [384][384]
  bf16* owt  = (bf16*)alloc(147456 / 2);
  bf16* cw1t = (bf16*)alloc(3 * W1SZ / 2);  // [1536][384] x3
  bf16* cw2t = (bf16*)alloc(3 * W2SZ / 2);  // [384][1536] x3
  float* H1s = alloc(MS * 1536);
  float* DAs = alloc(MS * 1536);
  float* ODs = alloc(MS * 384);
  float* T2s = alloc(MS * 384);

  hipMemcpyAsync(SW1, tW1, 5 * W1SZ * 4, hipMemcpyDeviceToDevice, stream);
  hipMemcpyAsync(SB1, tb1, 5 * 1536 * 4, hipMemcpyDeviceToDevice, stream);
  hipMemcpyAsync(SW2, tW2, 5 * W2SZ * 4, hipMemcpyDeviceToDevice, stream);
  hipMemcpyAsync(SB2, tb2, 5 * 384 * 4, hipMemcpyDeviceToDevice, stream);

  // static weight preps
  trans_w<<<dim3(12, 12), 256, 0, stream>>>(qW, qwt, 384, 384);
  trans_w<<<dim3(12, 12), 256, 0, stream>>>(outW, owt, 384, 384);
  for (int lcm = 0; lcm < 3; ++lcm) {
    trans_w<<<dim3(48, 12), 256, 0, stream>>>(cW1 + lcm * W1SZ, cw1t + lcm * W1SZ, 384, 1536);
    trans_w<<<dim3(12, 48), 256, 0, stream>>>(cW2 + lcm * W2SZ, cw2t + lcm * W2SZ, 1536, 384);
  }

  const size_t grads_bytes = STATE * 4;
  const int gm = (int)(MS / 128);
  const int mlen = (MS >= 2048) ? 2048 : (int)MS;
  const int zb = (int)(MS / mlen);
  const int nMS = (int)(MS * 384);

  for (int c = 0; c < 4; ++c) {
    hipMemsetAsync(G1, 0, grads_bytes, stream);
    hipMemsetAsync(RED, 0, 64, stream);

    // per-chunk state weight preps (state updated at end of previous chunk)
    for (int i = 0; i < 5; ++i) {
      trans_w<<<dim3(48, 12), 256, 0, stream>>>(SW1 + i * W1SZ, sw1t + i * W1SZ, 384, 1536);
      trans_w<<<dim3(12, 48), 256, 0, stream>>>(SW2 + i * W2SZ, sw2t + i * W2SZ, 1536, 384);
    }
    copy_bf16<<<dim3((int)(5 * W2SZ / 1024)), 256, 0, stream>>>(SW2, sw2c, (int)(5 * W2SZ));

    ln_kernel<<<dim3(16384), dim3(64), 0, stream>>>(x, n1g, n1b, Yc, 11, c * 2048, 8192);

    // ---- gen: k, v, eta(mean), alpha(mean) ----
    for (int i = 0; i < 4; ++i) {
      for (int s = 0; s < NS; ++s) {
        const float* Ys = Yc + (size_t)s * MS * 384;
        mm_fwd<false><<<dim3(gm, 12), 256, 0, stream>>>(Ys, sw1t + i * W1SZ,
            SB1 + i * 1536, nullptr, H1s, 384, 1536, 0, 30, 0, 0);
        float* dst = (i == 0) ? Kb + (size_t)s * MS * 384
                   : (i == 1) ? Vb + (size_t)s * MS * 384 : ODs;
        mm_fwd<true><<<dim3(gm, 3), 256, 0, stream>>>(H1s, sw2t + i * W2SZ,
            SB2 + i * 384, nullptr, dst, 1536, 384, 0, 30, 0, 0);
        if (i == 2) reduce_act<<<dim3(256), 256, 0, stream>>>(ODs, RED + 0, nMS, 0);
        if (i == 3) reduce_act<<<dim3(256), 256, 0, stream>>>(ODs, RED + 1, nMS, 1);
      }
    }

    // ---- q = yc @ qW (into Tt), rope(q, k) ----
    for (int s = 0; s < NS; ++s)
      mm_fwd<false><<<dim3(gm, 3), 256, 0, stream>>>(Yc + (size_t)s * MS * 384, qwt,
          nullptr, nullptr, Tt + (size_t)s * MS * 384, 384, 384, 0, 30, 0, 0);
    rope_kernel<<<dim3(1024), 256, 0, stream>>>(Tt, Kb);

    // ---- out = mlp4(q) -> proj + residual scatter into d_out ----
    for (int s = 0; s < NS; ++s) {
      mm_fwd<false><<<dim3(gm, 12), 256, 0, stream>>>(Tt + (size_t)s * MS * 384,
          sw1t + 4 * W1SZ, SB1 + 4 * 1536, nullptr, H1s, 384, 1536, 0, 30, 0, 0);
      mm_fwd<true><<<dim3(gm, 3), 256, 0, stream>>>(H1s, sw2t + 4 * W2SZ,
          SB2 + 4 * 384, nullptr, T2s, 1536, 384, 0, 30, 0, 0);
      mm_fwd<false><<<dim3(gm, 3), 256, 0, stream>>>(T2s, owt, outb, x, out,
          384, 384, (int)(s * MS), 11, c * 2048, 8192);
    }

    // ---- per-memory: target then grads ----
    for (int i = 0; i < 5; ++i) {
      if (i < 4) {
        for (int s = 0; s < NS; ++s) {
          mm_fwd<false><<<dim3(gm, 12), 256, 0, stream>>>(Vb + (size_t)s * MS * 384,
              sw1t + i * W1SZ, SB1 + i * 1536, nullptr, H1s, 384, 1536, 0, 30, 0, 0);
          mm_fwd<true><<<dim3(gm, 3), 256, 0, stream>>>(H1s, sw2t + i * W2SZ,
              SB2 + i * 384, nullptr, Tt + (size_t)s * MS * 384, 1536, 384, 0, 30, 0, 0);
        }
      }
      for (int s = 0; s < NS; ++s) {
        const float* Ks = Kb + (size_t)s * MS * 384;
        mm_fwd<false><<<dim3(gm, 12), 256, 0, stream>>>(Ks, sw1t + i * W1SZ,
            SB1 + i * 1536, nullptr, H1s, 384, 1536, 0, 30, 0, 0);
        mm_fwd<true><<<dim3(gm, 3), 256, 0, stream>>>(H1s, sw2t + i * W2SZ,
            SB2 + i * 384, nullptr, ODs, 1536, 384, 0, 30, 0, 0);
        const float* tg = ((i < 4) ? Tt : Vb) + (size_t)s * MS * 384;
        do_kernel<<<dim3(256), 256, 0, stream>>>(ODs, tg, nMS);
        colsum<<<dim3(3, (int)(MS / 256)), 128, 0, stream>>>(ODs, G4 + i * 384, 384, 256);
        mm_tn<true><<<dim3(12, 3, zb), 256, 0, stream>>>(H1s, ODs, G3 + i * W2SZ,
            1536, 384, mlen);
        mm_fwd<false><<<dim3(gm, 12), 256, 0, stream>>>(ODs, sw2c + i * W2SZ,
            nullptr, nullptr, DAs, 384, 1536, 0, 30, 0, 0);
        dh1_kernel<<<dim3(512), 256, 0, stream>>>(DAs, H1s, (int)(MS * 1536));
        colsum<<<dim3(12, (int)(MS / 256)), 128, 0, stream>>>(DAs, G2 + i * 1536, 1536, 256);
        mm_tn<false><<<dim3(3, 12, zb), 256, 0, stream>>>(Ks, DAs, G1 + i * W1SZ,
            384, 1536, mlen);
      }
    }

    // ---- norms + state update ----
    sumsq5<<<dim3(256, 5), 256, 0, stream>>>(G1, RED, (int)W1SZ);
    sumsq5<<<dim3(2, 5), 256, 0, stream>>>(G2, RED, 1536);
    sumsq5<<<dim3(256, 5), 256, 0, stream>>>(G3, RED, (int)W2SZ);
    sumsq5<<<dim3(2, 5), 256, 0, stream>>>(G4, RED, 384);
    update5<<<dim3(512, 5), 256, 0, stream>>>(SW1, G1, RED, (int)W1SZ);
    update5<<<dim3(4, 5), 256, 0, stream>>>(SB1, G2, RED, 1536);
    update5<<<dim3(512, 5), 256, 0, stream>>>(SW2, G3, RED, (int)W2SZ);
    update5<<<dim3(4, 5), 256, 0, stream>>>(SB2, G4, RED, 384);
  }

  // ---- norm2 + 3 CMS MLP layers + final residual, per MS-row slice ----
  const int NCS = (int)(65536 / MS);
  for (int s = 0; s < NCS; ++s) {
    float* hc = ODs; float* hn = T2s;
    ln_kernel<<<dim3((int)MS), dim3(64), 0, stream>>>(out, n2g, n2b, hc, 30, (int)(s * MS), 0);
    for (int lcm = 0; lcm < 3; ++lcm) {
      mm_fwd<false><<<dim3(gm, 12), 256, 0, stream>>>(hc, cw1t + lcm * W1SZ,
          cb1 + lcm * 1536, nullptr, H1s, 384, 1536, 0, 30, 0, 0);
      mm_fwd<true><<<dim3(gm, 3), 256, 0, stream>>>(H1s, cw2t + lcm * W2SZ,
          cb2 + lcm * 384, nullptr, hn, 1536, 384, 0, 30, 0, 0);
      float* t = hc; hc = hn; hn = t;
    }
    final_add<<<dim3(512), 256, 0, stream>>>(out + (size_t)s * MS * 384, hc, nMS);
  }
}

// Round 4
// 15370.389 us; speedup vs baseline: 5.0385x; 2.2160x over previous
//
#include <hip/hip_runtime.h>
#include <cstddef>
#include <cstdint>

// ---------------------------------------------------------------------------
// HOPE block forward. bf16 activations + bf16-MFMA GEMMs (global_load_lds,
// XOR-swizzled LDS), fp32 state/grads/reductions.
// B=8, N=8192, DIM=384, HID=1536, 4 chunks, rows/chunk = 16384.
// ---------------------------------------------------------------------------

typedef __bf16 bf16;
typedef __bf16 bf16x4 __attribute__((ext_vector_type(4)));
typedef __bf16 bf16x8 __attribute__((ext_vector_type(8)));
typedef float  f32x4  __attribute__((ext_vector_type(4)));

constexpr float INV_CNT = 1.0f / 6291456.0f;   // 1/(16384*384)

__device__ __forceinline__ float fast_gelu(float x) {
  float u = 0.7978845608028654f * (x + 0.044715f * x * x * x);
  return x / (1.0f + __expf(-2.0f * u));
}
__device__ __forceinline__ float fast_gelu_grad(float x) {
  float x2 = x * x;
  float u = 0.7978845608028654f * (x + 0.044715f * x * x2);
  float s = 1.0f / (1.0f + __expf(-2.0f * u));
  return s + x * s * (1.0f - s) * 1.5957691216057308f * (1.0f + 0.134145f * x2);
}
__device__ __forceinline__ f32x4 gelu4(f32x4 v) {
  v[0] = fast_gelu(v[0]); v[1] = fast_gelu(v[1]);
  v[2] = fast_gelu(v[2]); v[3] = fast_gelu(v[3]);
  return v;
}
__device__ __forceinline__ bf16x4 tobf4(f32x4 v) {
  bf16x4 o; o[0] = (bf16)v[0]; o[1] = (bf16)v[1]; o[2] = (bf16)v[2]; o[3] = (bf16)v[3];
  return o;
}
__device__ __forceinline__ f32x4 tof4(bf16x4 v) {
  return f32x4{(float)v[0], (float)v[1], (float)v[2], (float)v[3]};
}

__device__ __forceinline__ void gload16(const bf16* g, void* lds) {
  __builtin_amdgcn_global_load_lds(
      (const __attribute__((address_space(1))) void*)g,
      (__attribute__((address_space(3))) void*)lds, 16, 0, 0);
}

// ---- LayerNorm: 1 wave per row; y[r](bf16) = LN(x[map(r)]) -----------------
__global__ __launch_bounds__(64)
void ln_kernel(const float* __restrict__ x, const float* __restrict__ g,
               const float* __restrict__ b, bf16* __restrict__ y,
               int shift, int base, int stride) {
  int r = blockIdx.x;
  int src = ((r >> shift) * stride) + base + (r & ((1 << shift) - 1));
  int lane = threadIdx.x;
  const float* xr = x + (size_t)src * 384;
  float vals[6];
  float s = 0.f, s2 = 0.f;
#pragma unroll
  for (int i = 0; i < 6; ++i) {
    float v = xr[lane + i * 64];
    vals[i] = v; s += v; s2 += v * v;
  }
#pragma unroll
  for (int o = 32; o > 0; o >>= 1) { s += __shfl_xor(s, o); s2 += __shfl_xor(s2, o); }
  float m = s * (1.0f / 384.0f);
  float var = s2 * (1.0f / 384.0f) - m * m;
  float rr = rsqrtf(var + 1e-5f);
  bf16* yr = y + (size_t)r * 384;
#pragma unroll
  for (int i = 0; i < 6; ++i) {
    int c = lane + i * 64;
    yr[c] = (bf16)((vals[i] - m) * rr * g[c] + b[c]);
  }
}

// ---- weight prep: transpose fp32 [R][C] -> bf16 [C][R] ---------------------
__global__ __launch_bounds__(256)
void trans_w(const float* __restrict__ in, bf16* __restrict__ out, int R, int C) {
  __shared__ float t[32][33];
  int c0 = blockIdx.x * 32, r0 = blockIdx.y * 32;
  int tr = threadIdx.x >> 3, tc = (threadIdx.x & 7) * 4;
  f32x4 v = *(const f32x4*)&in[(size_t)(r0 + tr) * C + c0 + tc];
  t[tr][tc + 0] = v[0]; t[tr][tc + 1] = v[1]; t[tr][tc + 2] = v[2]; t[tr][tc + 3] = v[3];
  __syncthreads();
  bf16x4 o;
  o[0] = (bf16)t[tc + 0][tr]; o[1] = (bf16)t[tc + 1][tr];
  o[2] = (bf16)t[tc + 2][tr]; o[3] = (bf16)t[tc + 3][tr];
  *(bf16x4*)&out[(size_t)(c0 + tr) * R + r0 + tc] = o;
}

__global__ __launch_bounds__(256)
void copy_bf16(const float* __restrict__ in, bf16* __restrict__ out, int n) {
  int i = (blockIdx.x * 256 + threadIdx.x) * 4;
  if (i < n) {
    f32x4 v = *(const f32x4*)&in[i];
    *(bf16x4*)&out[i] = tobf4(v);
  }
}

// ---- MFMA GEMM: D[i][m] = sum_k W[i][k] * Act[m][k], fused epilogues -------
// Act bf16 [M][K] contiguous, W bf16 [Itot][K]. BM=BN=128, BK=64.
// LDS tiles [128 rows][128 B], XOR-swizzled: byte ^= ((row&7)<<4); staged via
// global_load_lds(16B) with pre-swizzled per-lane global source (rule #21).
enum { E_BF16 = 0, E_GELU, E_PAIR, E_SUB, E_SP, E_SIG, E_MUL, E_F32ADD };

template <int EPI>
__global__ __launch_bounds__(256)
void mm_fwd(const bf16* __restrict__ Act, const bf16* __restrict__ W,
            const float* __restrict__ bias, const bf16* __restrict__ baux,
            const float* __restrict__ faux, float* __restrict__ red,
            bf16* __restrict__ Cb, bf16* __restrict__ C2, float* __restrict__ Cf,
            int K, int ldc, float scale,
            int croff, int cshift, int cbase, int cstride) {
  __shared__ bf16 sW[128 * 64];
  __shared__ bf16 sA[128 * 64];
  __shared__ float sT[4][16][68];
  const int tid = threadIdx.x;
  const int m0 = blockIdx.x * 128, i0 = blockIdx.y * 128;
  const int l = tid & 63, w = tid >> 6;
  const int a = l & 15, g = l >> 4;
  const int wi0 = (w & 1) * 64, wm0 = (w >> 1) * 64;

  // staging geometry: lane l, segment seg=w*4+t covers LDS [seg*1024, +1024)
  const int lrow = l >> 3;                        // row within segment
  const int lcol = ((l & 7) ^ lrow) << 4;         // pre-swizzled byte in row
  const int lcolel = lcol >> 1;                   // bf16 elements

  f32x4 acc[4][4];
#pragma unroll
  for (int i = 0; i < 4; ++i)
#pragma unroll
    for (int j = 0; j < 4; ++j) acc[i][j] = f32x4{0.f, 0.f, 0.f, 0.f};

  for (int k0 = 0; k0 < K; k0 += 64) {
#pragma unroll
    for (int t = 0; t < 4; ++t) {
      const int seg = w * 4 + t;
      const int row = seg * 8 + lrow;
      gload16(W   + (size_t)(i0 + row) * K + k0 + lcolel, (char*)sW + seg * 1024);
      gload16(Act + (size_t)(m0 + row) * K + k0 + lcolel, (char*)sA + seg * 1024);
    }
    __syncthreads();   // compiler drains vmcnt(0) before barrier (m97 semantics)
#pragma unroll
    for (int kh = 0; kh < 2; ++kh) {
      bf16x8 Af[4], Bf[4];
#pragma unroll
      for (int f = 0; f < 4; ++f) {
        const int rW = wi0 + f * 16 + a;
        Af[f] = *(const bf16x8*)((const char*)sW +
                 ((rW * 128 + kh * 64 + g * 16) ^ ((rW & 7) << 4)));
        const int rA = wm0 + f * 16 + a;
        Bf[f] = *(const bf16x8*)((const char*)sA +
                 ((rA * 128 + kh * 64 + g * 16) ^ ((rA & 7) << 4)));
      }
#pragma unroll
      for (int fi = 0; fi < 4; ++fi)
#pragma unroll
        for (int fm = 0; fm < 4; ++fm)
          acc[fi][fm] = __builtin_amdgcn_mfma_f32_16x16x32_bf16(Af[fi], Bf[fm], acc[fi][fm], 0, 0, 0);
    }
    __syncthreads();
  }

  // acc[fi][fm][r] = D for i = i0+wi0+fi*16+g*4+r, m = m0+wm0+fm*16+a
  if constexpr (EPI == E_SP || EPI == E_SIG) {
    float ssum = 0.f;
#pragma unroll
    for (int fi = 0; fi < 4; ++fi) {
      f32x4 b4 = *(const f32x4*)&bias[i0 + wi0 + fi * 16 + g * 4];
#pragma unroll
      for (int fm = 0; fm < 4; ++fm)
#pragma unroll
        for (int r = 0; r < 4; ++r) {
          float vv = acc[fi][fm][r] + b4[r];
          if constexpr (EPI == E_SP)
            ssum += fmaxf(vv, 0.f) + log1pf(__expf(-fabsf(vv)));
          else
            ssum += 1.0f / (1.0f + __expf(-vv));
        }
    }
#pragma unroll
    for (int o = 32; o > 0; o >>= 1) ssum += __shfl_xor(ssum, o);
    float* wred = (float*)sT;
    if (l == 0) wred[w] = ssum;
    __syncthreads();
    if (tid == 0) atomicAdd(red, wred[0] + wred[1] + wred[2] + wred[3]);
    return;
  } else {
    // transpose epilogue (per-wave LDS slab) -> coalesced row-major stores
    float* T = &sT[w][0][0];
    const int iB = i0 + wi0;
    f32x4 b4 = f32x4{0.f, 0.f, 0.f, 0.f};
    if (bias) b4 = *(const f32x4*)&bias[iB + a * 4];
#pragma unroll
    for (int fm = 0; fm < 4; ++fm) {
#pragma unroll
      for (int fi = 0; fi < 4; ++fi)
        *(f32x4*)&T[a * 68 + fi * 16 + g * 4] = acc[fi][fm];
      asm volatile("s_waitcnt lgkmcnt(0)" ::: "memory");
#pragma unroll
      for (int q = 0; q < 4; ++q) {
        const int ml = wm0 + fm * 16 + q * 4 + g;
        f32x4 v = *(const f32x4*)&T[(q * 4 + g) * 68 + a * 4];
        v += b4;
        if constexpr (EPI == E_F32ADD) {
          const int rr = croff + m0 + ml;
          const int crow = ((rr >> cshift) * cstride) + cbase + (rr & ((1 << cshift) - 1));
          const size_t cb = (size_t)crow * ldc + iB + a * 4;
          v += *(const f32x4*)&faux[cb];
          *(f32x4*)&Cf[cb] = v;
        } else {
          const size_t cb = (size_t)(m0 + ml) * ldc + iB + a * 4;
          if constexpr (EPI == E_BF16) {
            *(bf16x4*)&Cb[cb] = tobf4(v);
          } else if constexpr (EPI == E_GELU) {
            *(bf16x4*)&Cb[cb] = tobf4(gelu4(v));
          } else if constexpr (EPI == E_PAIR) {
            *(bf16x4*)&Cb[cb] = tobf4(v);
            *(bf16x4*)&C2[cb] = tobf4(gelu4(v));
          } else if constexpr (EPI == E_SUB) {
            f32x4 t4 = tof4(*(const bf16x4*)&baux[cb]);
            v = (v - t4) * scale;
            *(bf16x4*)&Cb[cb] = tobf4(v);
          } else if constexpr (EPI == E_MUL) {
            f32x4 h4 = tof4(*(const bf16x4*)&baux[cb]);
            v[0] *= fast_gelu_grad(h4[0]); v[1] *= fast_gelu_grad(h4[1]);
            v[2] *= fast_gelu_grad(h4[2]); v[3] *= fast_gelu_grad(h4[3]);
            *(bf16x4*)&Cb[cb] = tobf4(v);
          }
        }
      }
    }
  }
}

// ---- MFMA GEMM TN: G[i1][i2] += sum_m A[m][i1] * B[m][i2]  (atomics) -------
__global__ __launch_bounds__(256)
void mm_tn(const bf16* __restrict__ A, const bf16* __restrict__ B,
           float* __restrict__ G, int lda, int ldb, int mlen) {
  __shared__ bf16 s1[128][40];
  __shared__ bf16 s2[128][40];
  const int tid = threadIdx.x;
  const int i1o = blockIdx.x * 128, i2o = blockIdx.y * 128;
  const int mb = blockIdx.z * mlen;
  const int iq = (tid & 31) * 4, mq = (tid >> 5) * 4;
  const int l = tid & 63, w = tid >> 6;
  const int a = l & 15, g = l >> 4;
  const int w1 = (w & 1) * 64, w2 = (w >> 1) * 64;

  f32x4 acc[4][4];
#pragma unroll
  for (int i = 0; i < 4; ++i)
#pragma unroll
    for (int j = 0; j < 4; ++j) acc[i][j] = f32x4{0.f, 0.f, 0.f, 0.f};

  for (int m0 = 0; m0 < mlen; m0 += 32) {
    {
      const bf16* p = A + (size_t)(mb + m0 + mq) * lda + i1o + iq;
      bf16x4 r0 = *(const bf16x4*)(p);
      bf16x4 r1 = *(const bf16x4*)(p + lda);
      bf16x4 r2 = *(const bf16x4*)(p + 2 * (size_t)lda);
      bf16x4 r3 = *(const bf16x4*)(p + 3 * (size_t)lda);
#pragma unroll
      for (int c2 = 0; c2 < 4; ++c2) {
        bf16x4 o; o[0] = r0[c2]; o[1] = r1[c2]; o[2] = r2[c2]; o[3] = r3[c2];
        *(bf16x4*)&s1[iq + c2][mq] = o;
      }
    }
    {
      const bf16* p = B + (size_t)(mb + m0 + mq) * ldb + i2o + iq;
      bf16x4 r0 = *(const bf16x4*)(p);
      bf16x4 r1 = *(const bf16x4*)(p + ldb);
      bf16x4 r2 = *(const bf16x4*)(p + 2 * (size_t)ldb);
      bf16x4 r3 = *(const bf16x4*)(p + 3 * (size_t)ldb);
#pragma unroll
      for (int c2 = 0; c2 < 4; ++c2) {
        bf16x4 o; o[0] = r0[c2]; o[1] = r1[c2]; o[2] = r2[c2]; o[3] = r3[c2];
        *(bf16x4*)&s2[iq + c2][mq] = o;
      }
    }
    __syncthreads();
    bf16x8 Af[4], Bf[4];
#pragma unroll
    for (int f = 0; f < 4; ++f) {
      Af[f] = *(const bf16x8*)&s1[w1 + f * 16 + a][g * 8];
      Bf[f] = *(const bf16x8*)&s2[w2 + f * 16 + a][g * 8];
    }
#pragma unroll
    for (int f1 = 0; f1 < 4; ++f1)
#pragma unroll
      for (int f2 = 0; f2 < 4; ++f2)
        acc[f1][f2] = __builtin_amdgcn_mfma_f32_16x16x32_bf16(Af[f1], Bf[f2], acc[f1][f2], 0, 0, 0);
    __syncthreads();
  }
#pragma unroll
  for (int f1 = 0; f1 < 4; ++f1)
#pragma unroll
    for (int f2 = 0; f2 < 4; ++f2)
#pragma unroll
      for (int r = 0; r < 4; ++r)
        atomicAdd(&G[(size_t)(i1o + w1 + f1 * 16 + g * 4 + r) * ldb + i2o + w2 + f2 * 16 + a],
                  acc[f1][f2][r]);
}

// ---- RoPE in place on q and k (bf16, full chunk) ---------------------------
__global__ __launch_bounds__(256)
void rope_kernel(bf16* __restrict__ q, bf16* __restrict__ k) {
  int idx = blockIdx.x * blockDim.x + threadIdx.x;   // 262144
  int row = idx >> 4, hd = idx & 15;
  int j = row & 2047;
  float pos[3] = { (float)(j >> 8), (float)((j >> 4) & 15), (float)(j & 15) };
  const float freqs[4] = { 1.0f, 0.1f, 0.01f, 0.001f };
  size_t base = (size_t)row * 384 + hd * 24;
  bf16* ptrs[2] = { q + base, k + base };
#pragma unroll
  for (int m2 = 0; m2 < 2; ++m2) {
    bf16* p = ptrs[m2];
#pragma unroll
    for (int s = 0; s < 3; ++s) {
      bf16x8 vv = *(bf16x8*)(p + s * 8);
#pragma unroll
      for (int pr = 0; pr < 4; ++pr) {
        float ang = pos[s] * freqs[pr];
        float si, co;
        sincosf(ang, &si, &co);
        float e0 = (float)vv[2 * pr], e1 = (float)vv[2 * pr + 1];
        vv[2 * pr]     = (bf16)(e0 * co - e1 * si);
        vv[2 * pr + 1] = (bf16)(e0 * si + e1 * co);
      }
      *(bf16x8*)(p + s * 8) = vv;
    }
  }
}

// ---- reductions -------------------------------------------------------------
__global__ __launch_bounds__(128)
void colsum_bf(const bf16* __restrict__ A, float* __restrict__ out, int ncols, int rpb) {
  int col = blockIdx.x * 128 + threadIdx.x;
  if (col >= ncols) return;
  int r0 = blockIdx.y * rpb;
  float s = 0.f;
  for (int r = r0; r < r0 + rpb; ++r) s += (float)A[(size_t)r * ncols + col];
  atomicAdd(&out[col], s);
}

__global__ __launch_bounds__(256)
void sumsq5(const float* __restrict__ G, float* __restrict__ red, int per_i) {
  int i = blockIdx.y;
  const float* base = G + (size_t)i * per_i;
  float s = 0.f;
  for (int idx = blockIdx.x * blockDim.x + threadIdx.x; idx < per_i; idx += gridDim.x * blockDim.x) {
    float v = base[idx]; s += v * v;
  }
  __shared__ float sm[256];
  sm[threadIdx.x] = s; __syncthreads();
  for (int o = 128; o > 0; o >>= 1) {
    if (threadIdx.x < o) sm[threadIdx.x] += sm[threadIdx.x + o];
    __syncthreads();
  }
  if (threadIdx.x == 0) atomicAdd(&red[2 + i], sm[0]);
}

__global__ __launch_bounds__(256)
void update5(float* __restrict__ S, const float* __restrict__ G,
             const float* __restrict__ red, int per_i) {
  int i = blockIdx.y;
  size_t base = (size_t)i * per_i;
  float em = 0.01f * red[0] * INV_CNT;
  float am = red[1] * INV_CNT;
  float norm = sqrtf(red[2 + i]);
  float sc = fminf(1.0f, 1.0f / (norm + 1e-12f));
  float ws_ = 1.0f - am;
  float gs = em * sc;
  for (int idx = blockIdx.x * blockDim.x + threadIdx.x; idx < per_i; idx += gridDim.x * blockDim.x)
    S[base + idx] = ws_ * S[base + idx] - gs * G[base + idx];
}

// ---------------------------------------------------------------------------
extern "C" void kernel_launch(void* const* d_in, const int* in_sizes, int n_in,
                              void* d_out, int out_size, void* d_ws, size_t ws_size,
                              hipStream_t stream) {
  const float* x    = (const float*)d_in[0];
  const float* n1g  = (const float*)d_in[1];
  const float* n1b  = (const float*)d_in[2];
  const float* qW   = (const float*)d_in[3];
  const float* tW1  = (const float*)d_in[4];
  const float* tb1  = (const float*)d_in[5];
  const float* tW2  = (const float*)d_in[6];
  const float* tb2  = (const float*)d_in[7];
  const float* outW = (const float*)d_in[8];
  const float* outb = (const float*)d_in[9];
  const float* n2g  = (const float*)d_in[10];
  const float* n2b  = (const float*)d_in[11];
  const float* cW1  = (const float*)d_in[12];
  const float* cb1  = (const float*)d_in[13];
  const float* cW2  = (const float*)d_in[14];
  const float* cb2  = (const float*)d_in[15];
  float* out = (float*)d_out;

  const size_t W1SZ = 384 * 1536, W2SZ = 1536 * 384;
  const size_t STATE = 5 * W1SZ + 5 * 1536 + 5 * W2SZ + 5 * 384;
  const size_t BF_W = 15 * W1SZ + 2 * 147456 + 6 * W1SZ;          // bf16 weight elems
  const size_t CHUNK_BF = 4 * (size_t)16384 * 384;                // Yc,Kb,Vb,Tt
  const size_t FIXEDF = 2 * STATE + 16 + BF_W / 2 + CHUNK_BF / 2; // f32 units

  size_t MS = 16384;
  while (MS > 2048 && (FIXEDF + MS * 2688) * 4 > ws_size) MS >>= 1;
  if ((FIXEDF + MS * 2688) * 4 > ws_size) {
    hipMemcpyAsync(d_out, d_in[0], (size_t)25165824 * 4, hipMemcpyDeviceToDevice, stream);
    return;
  }
  const int NS = (int)(16384 / MS);

  float* ws = (float*)d_ws;
  size_t off = 0;
  auto alloc = [&](size_t n) { float* p = ws + off; off += n; return p; };
  auto balloc = [&](size_t n) { bf16* p = (bf16*)(ws + off); off += (n + 1) / 2; return p; };
  float* SW1 = alloc(5 * W1SZ);
  float* SB1 = alloc(5 * 1536);
  float* SW2 = alloc(5 * W2SZ);
  float* SB2 = alloc(5 * 384);
  float* G1  = alloc(5 * W1SZ);     // G1..G4 contiguous (single memset)
  float* G2  = alloc(5 * 1536);
  float* G3  = alloc(5 * W2SZ);
  float* G4  = alloc(5 * 384);
  float* RED = alloc(16);
  bf16* Yc   = balloc((size_t)16384 * 384);
  bf16* Kb   = balloc((size_t)16384 * 384);
  bf16* Vb   = balloc((size_t)16384 * 384);
  bf16* Tt   = balloc((size_t)16384 * 384);  // q, then per-memory targets
  bf16* sw1t = balloc(5 * W1SZ);   // [1536][384]
  bf16* sw2t = balloc(5 * W2SZ);   // [384][1536]
  bf16* sw2c = balloc(5 * W2SZ);   // [1536][384] straight copy
  bf16* qwt  = balloc(147456);     // [384][384]
  bf16* owt  = balloc(147456);
  bf16* cw1t = balloc(3 * W1SZ);
  bf16* cw2t = balloc(3 * W2SZ);
  bf16* H1r  = balloc(MS * 1536);
  bf16* GH1  = balloc(MS * 1536);
  bf16* DA   = balloc(MS * 1536);
  bf16* OD   = balloc(MS * 384);
  bf16* T2   = balloc(MS * 384);

  hipMemcpyAsync(SW1, tW1, 5 * W1SZ * 4, hipMemcpyDeviceToDevice, stream);
  hipMemcpyAsync(SB1, tb1, 5 * 1536 * 4, hipMemcpyDeviceToDevice, stream);
  hipMemcpyAsync(SW2, tW2, 5 * W2SZ * 4, hipMemcpyDeviceToDevice, stream);
  hipMemcpyAsync(SB2, tb2, 5 * 384 * 4, hipMemcpyDeviceToDevice, stream);

  // static weight preps
  trans_w<<<dim3(12, 12), 256, 0, stream>>>(qW, qwt, 384, 384);
  trans_w<<<dim3(12, 12), 256, 0, stream>>>(outW, owt, 384, 384);
  for (int lc = 0; lc < 3; ++lc) {
    trans_w<<<dim3(48, 12), 256, 0, stream>>>(cW1 + lc * W1SZ, cw1t + lc * W1SZ, 384, 1536);
    trans_w<<<dim3(12, 48), 256, 0, stream>>>(cW2 + lc * W2SZ, cw2t + lc * W2SZ, 1536, 384);
  }

  const size_t grads_bytes = STATE * 4;
  const int gm = (int)(MS / 128);
  const int mlen = (MS >= 2048) ? 2048 : (int)MS;
  const int zb = (int)(MS / mlen);
  const float SC = 2.0f * INV_CNT;

  for (int c = 0; c < 4; ++c) {
    hipMemsetAsync(G1, 0, grads_bytes, stream);
    hipMemsetAsync(RED, 0, 64, stream);
    for (int i = 0; i < 5; ++i) {
      trans_w<<<dim3(48, 12), 256, 0, stream>>>(SW1 + i * W1SZ, sw1t + i * W1SZ, 384, 1536);
      trans_w<<<dim3(12, 48), 256, 0, stream>>>(SW2 + i * W2SZ, sw2t + i * W2SZ, 1536, 384);
    }
    copy_bf16<<<dim3(2880), 256, 0, stream>>>(SW2, sw2c, (int)(5 * W2SZ));

    ln_kernel<<<dim3(16384), dim3(64), 0, stream>>>(x, n1g, n1b, Yc, 11, c * 2048, 8192);

    // ---- gen: k, v, eta(mean), alpha(mean) ----
    for (int i = 0; i < 4; ++i) {
      for (int s = 0; s < NS; ++s) {
        const bf16* Ys = Yc + (size_t)s * MS * 384;
        mm_fwd<E_GELU><<<dim3(gm, 12), 256, 0, stream>>>(Ys, sw1t + i * W1SZ,
            SB1 + i * 1536, nullptr, nullptr, nullptr, GH1, nullptr, nullptr,
            384, 1536, 0.f, 0, 30, 0, 0);
        if (i == 0)
          mm_fwd<E_BF16><<<dim3(gm, 3), 256, 0, stream>>>(GH1, sw2t + i * W2SZ,
              SB2 + i * 384, nullptr, nullptr, nullptr, Kb + (size_t)s * MS * 384,
              nullptr, nullptr, 1536, 384, 0.f, 0, 30, 0, 0);
        else if (i == 1)
          mm_fwd<E_BF16><<<dim3(gm, 3), 256, 0, stream>>>(GH1, sw2t + i * W2SZ,
              SB2 + i * 384, nullptr, nullptr, nullptr, Vb + (size_t)s * MS * 384,
              nullptr, nullptr, 1536, 384, 0.f, 0, 30, 0, 0);
        else if (i == 2)
          mm_fwd<E_SP><<<dim3(gm, 3), 256, 0, stream>>>(GH1, sw2t + i * W2SZ,
              SB2 + i * 384, nullptr, nullptr, RED + 0, nullptr, nullptr, nullptr,
              1536, 384, 0.f, 0, 30, 0, 0);
        else
          mm_fwd<E_SIG><<<dim3(gm, 3), 256, 0, stream>>>(GH1, sw2t + i * W2SZ,
              SB2 + i * 384, nullptr, nullptr, RED + 1, nullptr, nullptr, nullptr,
              1536, 384, 0.f, 0, 30, 0, 0);
      }
    }

    // ---- q = yc @ qW (into Tt), rope(q, k) ----
    for (int s = 0; s < NS; ++s)
      mm_fwd<E_BF16><<<dim3(gm, 3), 256, 0, stream>>>(Yc + (size_t)s * MS * 384, qwt,
          nullptr, nullptr, nullptr, nullptr, Tt + (size_t)s * MS * 384, nullptr, nullptr,
          384, 384, 0.f, 0, 30, 0, 0);
    rope_kernel<<<dim3(1024), 256, 0, stream>>>(Tt, Kb);

    // ---- out = mlp4(q) -> proj + residual scatter into d_out ----
    for (int s = 0; s < NS; ++s) {
      mm_fwd<E_GELU><<<dim3(gm, 12), 256, 0, stream>>>(Tt + (size_t)s * MS * 384,
          sw1t + 4 * W1SZ, SB1 + 4 * 1536, nullptr, nullptr, nullptr, GH1, nullptr, nullptr,
          384, 1536, 0.f, 0, 30, 0, 0);
      mm_fwd<E_BF16><<<dim3(gm, 3), 256, 0, stream>>>(GH1, sw2t + 4 * W2SZ,
          SB2 + 4 * 384, nullptr, nullptr, nullptr, T2, nullptr, nullptr,
          1536, 384, 0.f, 0, 30, 0, 0);
      mm_fwd<E_F32ADD><<<dim3(gm, 3), 256, 0, stream>>>(T2, owt, outb,
          nullptr, x, nullptr, nullptr, nullptr, out,
          384, 384, 0.f, (int)(s * MS), 11, c * 2048, 8192);
    }

    // ---- per-memory: target then grads ----
    for (int i = 0; i < 5; ++i) {
      if (i < 4) {
        for (int s = 0; s < NS; ++s) {
          mm_fwd<E_GELU><<<dim3(gm, 12), 256, 0, stream>>>(Vb + (size_t)s * MS * 384,
              sw1t + i * W1SZ, SB1 + i * 1536, nullptr, nullptr, nullptr, GH1, nullptr, nullptr,
              384, 1536, 0.f, 0, 30, 0, 0);
          mm_fwd<E_BF16><<<dim3(gm, 3), 256, 0, stream>>>(GH1, sw2t + i * W2SZ,
              SB2 + i * 384, nullptr, nullptr, nullptr, Tt + (size_t)s * MS * 384,
              nullptr, nullptr, 1536, 384, 0.f, 0, 30, 0, 0);
        }
      }
      for (int s = 0; s < NS; ++s) {
        const bf16* Ks = Kb + (size_t)s * MS * 384;
        const bf16* tg = ((i < 4) ? Tt : Vb) + (size_t)s * MS * 384;
        mm_fwd<E_PAIR><<<dim3(gm, 12), 256, 0, stream>>>(Ks, sw1t + i * W1SZ,
            SB1 + i * 1536, nullptr, nullptr, nullptr, H1r, GH1, nullptr,
            384, 1536, 0.f, 0, 30, 0, 0);
        mm_fwd<E_SUB><<<dim3(gm, 3), 256, 0, stream>>>(GH1, sw2t + i * W2SZ,
            SB2 + i * 384, tg, nullptr, nullptr, OD, nullptr, nullptr,
            1536, 384, SC, 0, 30, 0, 0);
        colsum_bf<<<dim3(3, (int)(MS / 256)), 128, 0, stream>>>(OD, G4 + i * 384, 384, 256);
        mm_tn<<<dim3(12, 3, zb), 256, 0, stream>>>(GH1, OD, G3 + i * W2SZ, 1536, 384, mlen);
        mm_fwd<E_MUL><<<dim3(gm, 12), 256, 0, stream>>>(OD, sw2c + i * W2SZ,
            nullptr, H1r, nullptr, nullptr, DA, nullptr, nullptr,
            384, 1536, 0.f, 0, 30, 0, 0);
        colsum_bf<<<dim3(12, (int)(MS / 256)), 128, 0, stream>>>(DA, G2 + i * 1536, 1536, 256);
        mm_tn<<<dim3(3, 12, zb), 256, 0, stream>>>(Ks, DA, G1 + i * W1SZ, 384, 1536, mlen);
      }
    }

    // ---- norms + state update ----
    sumsq5<<<dim3(256, 5), 256, 0, stream>>>(G1, RED, (int)W1SZ);
    sumsq5<<<dim3(2, 5), 256, 0, stream>>>(G2, RED, 1536);
    sumsq5<<<dim3(256, 5), 256, 0, stream>>>(G3, RED, (int)W2SZ);
    sumsq5<<<dim3(2, 5), 256, 0, stream>>>(G4, RED, 384);
    update5<<<dim3(512, 5), 256, 0, stream>>>(SW1, G1, RED, (int)W1SZ);
    update5<<<dim3(4, 5), 256, 0, stream>>>(SB1, G2, RED, 1536);
    update5<<<dim3(512, 5), 256, 0, stream>>>(SW2, G3, RED, (int)W2SZ);
    update5<<<dim3(4, 5), 256, 0, stream>>>(SB2, G4, RED, 384);
  }

  // ---- norm2 + 3 CMS MLP layers (+ fused final residual), per MS slice ----
  const int NCS = (int)(65536 / MS);
  for (int s2 = 0; s2 < NCS; ++s2) {
    float* outp = out + (size_t)s2 * MS * 384;
    ln_kernel<<<dim3((int)MS), dim3(64), 0, stream>>>(out, n2g, n2b, OD, 30, (int)(s2 * MS), 0);
    bf16* hc = OD; bf16* hn = T2;
    for (int lc = 0; lc < 3; ++lc) {
      mm_fwd<E_GELU><<<dim3(gm, 12), 256, 0, stream>>>(hc, cw1t + lc * W1SZ,
          cb1 + lc * 1536, nullptr, nullptr, nullptr, GH1, nullptr, nullptr,
          384, 1536, 0.f, 0, 30, 0, 0);
      if (lc < 2) {
        mm_fwd<E_BF16><<<dim3(gm, 3), 256, 0, stream>>>(GH1, cw2t + lc * W2SZ,
            cb2 + lc * 384, nullptr, nullptr, nullptr, hn, nullptr, nullptr,
            1536, 384, 0.f, 0, 30, 0, 0);
        bf16* t = hc; hc = hn; hn = t;
      } else {
        mm_fwd<E_F32ADD><<<dim3(gm, 3), 256, 0, stream>>>(GH1, cw2t + lc * W2SZ,
            cb2 + lc * 384, nullptr, outp, nullptr, nullptr, nullptr, outp,
            1536, 384, 0.f, 0, 30, 0, 0);
      }
    }
  }
}

// Round 5
// 11994.514 us; speedup vs baseline: 6.4565x; 1.2815x over previous
//
#include <hip/hip_runtime.h>
#include <cstddef>
#include <cstdint>

// ---------------------------------------------------------------------------
// HOPE block forward. bf16 activations + bf16-MFMA GEMMs (global_load_lds,
// XOR-swizzled LDS). Weight-grad GEMMs run on transposed operands produced
// for free by the forward epilogues. fp32 state/grads/reductions.
// B=8, N=8192, DIM=384, HID=1536, 4 chunks, rows/chunk = 16384.
// ---------------------------------------------------------------------------

typedef __bf16 bf16;
typedef __bf16 bf16x4 __attribute__((ext_vector_type(4)));
typedef __bf16 bf16x8 __attribute__((ext_vector_type(8)));
typedef float  f32x4  __attribute__((ext_vector_type(4)));

constexpr float INV_CNT = 1.0f / 6291456.0f;   // 1/(16384*384)

__device__ __forceinline__ float fast_gelu(float x) {
  float u = 0.7978845608028654f * (x + 0.044715f * x * x * x);
  return x / (1.0f + __expf(-2.0f * u));
}
__device__ __forceinline__ float fast_gelu_grad(float x) {
  float x2 = x * x;
  float u = 0.7978845608028654f * (x + 0.044715f * x * x2);
  float s = 1.0f / (1.0f + __expf(-2.0f * u));
  return s + x * s * (1.0f - s) * 1.5957691216057308f * (1.0f + 0.134145f * x2);
}
__device__ __forceinline__ f32x4 gelu4(f32x4 v) {
  v[0] = fast_gelu(v[0]); v[1] = fast_gelu(v[1]);
  v[2] = fast_gelu(v[2]); v[3] = fast_gelu(v[3]);
  return v;
}
__device__ __forceinline__ bf16x4 tobf4(f32x4 v) {
  bf16x4 o; o[0] = (bf16)v[0]; o[1] = (bf16)v[1]; o[2] = (bf16)v[2]; o[3] = (bf16)v[3];
  return o;
}
__device__ __forceinline__ f32x4 tof4(bf16x4 v) {
  return f32x4{(float)v[0], (float)v[1], (float)v[2], (float)v[3]};
}

__device__ __forceinline__ void gload16(const bf16* g, void* lds) {
  __builtin_amdgcn_global_load_lds(
      (const __attribute__((address_space(1))) void*)g,
      (__attribute__((address_space(3))) void*)lds, 16, 0, 0);
}

// ---- LayerNorm: 1 wave per row; y[r](bf16) = LN(x[map(r)]) -----------------
__global__ __launch_bounds__(64)
void ln_kernel(const float* __restrict__ x, const float* __restrict__ g,
               const float* __restrict__ b, bf16* __restrict__ y,
               int shift, int base, int stride) {
  int r = blockIdx.x;
  int src = ((r >> shift) * stride) + base + (r & ((1 << shift) - 1));
  int lane = threadIdx.x;
  const float* xr = x + (size_t)src * 384;
  float vals[6];
  float s = 0.f, s2 = 0.f;
#pragma unroll
  for (int i = 0; i < 6; ++i) {
    float v = xr[lane + i * 64];
    vals[i] = v; s += v; s2 += v * v;
  }
#pragma unroll
  for (int o = 32; o > 0; o >>= 1) { s += __shfl_xor(s, o); s2 += __shfl_xor(s2, o); }
  float m = s * (1.0f / 384.0f);
  float var = s2 * (1.0f / 384.0f) - m * m;
  float rr = rsqrtf(var + 1e-5f);
  bf16* yr = y + (size_t)r * 384;
#pragma unroll
  for (int i = 0; i < 6; ++i) {
    int c = lane + i * 64;
    yr[c] = (bf16)((vals[i] - m) * rr * g[c] + b[c]);
  }
}

// ---- weight prep: transpose fp32 [R][C] -> bf16 [C][R] ---------------------
__global__ __launch_bounds__(256)
void trans_w(const float* __restrict__ in, bf16* __restrict__ out, int R, int C) {
  __shared__ float t[32][33];
  int c0 = blockIdx.x * 32, r0 = blockIdx.y * 32;
  int tr = threadIdx.x >> 3, tc = (threadIdx.x & 7) * 4;
  f32x4 v = *(const f32x4*)&in[(size_t)(r0 + tr) * C + c0 + tc];
  t[tr][tc + 0] = v[0]; t[tr][tc + 1] = v[1]; t[tr][tc + 2] = v[2]; t[tr][tc + 3] = v[3];
  __syncthreads();
  bf16x4 o;
  o[0] = (bf16)t[tc + 0][tr]; o[1] = (bf16)t[tc + 1][tr];
  o[2] = (bf16)t[tc + 2][tr]; o[3] = (bf16)t[tc + 3][tr];
  *(bf16x4*)&out[(size_t)(c0 + tr) * R + r0 + tc] = o;
}

// ---- transpose bf16 [R][C] -> bf16 [C][R] (for Kb -> Kbt after rope) -------
__global__ __launch_bounds__(256)
void tr_bf(const bf16* __restrict__ in, bf16* __restrict__ out, int R, int C) {
  __shared__ bf16 t[32][36];
  int r0 = blockIdx.x * 32, c0 = blockIdx.y * 32;
  int tr = threadIdx.x >> 3, tc = (threadIdx.x & 7) * 4;
  bf16x4 v = *(const bf16x4*)&in[(size_t)(r0 + tr) * C + c0 + tc];
  t[tr][tc + 0] = v[0]; t[tr][tc + 1] = v[1]; t[tr][tc + 2] = v[2]; t[tr][tc + 3] = v[3];
  __syncthreads();
  bf16x4 o;
  o[0] = t[tc + 0][tr]; o[1] = t[tc + 1][tr]; o[2] = t[tc + 2][tr]; o[3] = t[tc + 3][tr];
  *(bf16x4*)&out[(size_t)(c0 + tr) * R + r0 + tc] = o;
}

__global__ __launch_bounds__(256)
void copy_bf16(const float* __restrict__ in, bf16* __restrict__ out, int n) {
  int i = (blockIdx.x * 256 + threadIdx.x) * 4;
  if (i < n) {
    f32x4 v = *(const f32x4*)&in[i];
    *(bf16x4*)&out[i] = tobf4(v);
  }
}

// ---- MFMA GEMM: D[i][m] = sum_k W[i][k] * Act[m][k], fused epilogues -------
// Act bf16 [M][K], W bf16 [Itot][K]. Tile BM x 128, BK=64. LDS XOR-swizzled,
// staged via global_load_lds(16B) with pre-swizzled per-lane global source.
// Optional transposed output Ct[i][m] (ldt) built from the same f32 values.
enum { E_BF16 = 0, E_GELU, E_PAIR, E_SUB, E_SP, E_SIG, E_MUL, E_F32ADD };

template <int EPI, int BM>
__global__ __launch_bounds__(256)
void mm_fwd(const bf16* __restrict__ Act, const bf16* __restrict__ W,
            const float* __restrict__ bias, const bf16* __restrict__ baux,
            const float* __restrict__ faux, float* __restrict__ red,
            bf16* __restrict__ Cb, bf16* __restrict__ C2, bf16* __restrict__ Ct,
            float* __restrict__ Cf, int K, int ldc, int ldt, float scale,
            int croff, int cshift, int cbase, int cstride) {
  constexpr int WM = BM / 2;        // per-wave m extent
  constexpr int NFM = WM / 16;      // m fragments per wave
  constexpr int TA = BM / 32;       // sA gload segments per wave
  __shared__ bf16 sW[128 * 64];
  __shared__ bf16 sA[BM * 64];
  __shared__ float sT[4][16][68];
  const int tid = threadIdx.x;
  const int m0 = blockIdx.x * BM, i0 = blockIdx.y * 128;
  const int l = tid & 63, w = tid >> 6;
  const int a = l & 15, g = l >> 4;
  const int wi0 = (w & 1) * 64, wm0 = (w >> 1) * WM;

  const int lrow = l >> 3;
  const int lcolel = (((l & 7) ^ lrow) << 4) >> 1;

  f32x4 acc[4][NFM];
#pragma unroll
  for (int i = 0; i < 4; ++i)
#pragma unroll
    for (int j = 0; j < NFM; ++j) acc[i][j] = f32x4{0.f, 0.f, 0.f, 0.f};

  for (int k0 = 0; k0 < K; k0 += 64) {
#pragma unroll
    for (int t = 0; t < 4; ++t) {
      const int seg = w * 4 + t;
      gload16(W + (size_t)(i0 + seg * 8 + lrow) * K + k0 + lcolel, (char*)sW + seg * 1024);
    }
#pragma unroll
    for (int t = 0; t < TA; ++t) {
      const int seg = w * TA + t;
      gload16(Act + (size_t)(m0 + seg * 8 + lrow) * K + k0 + lcolel, (char*)sA + seg * 1024);
    }
    __syncthreads();
#pragma unroll
    for (int kh = 0; kh < 2; ++kh) {
      bf16x8 Af[4], Bf[NFM];
#pragma unroll
      for (int f = 0; f < 4; ++f) {
        const int rW = wi0 + f * 16 + a;
        Af[f] = *(const bf16x8*)((const char*)sW +
                 ((rW * 128 + kh * 64 + g * 16) ^ ((rW & 7) << 4)));
      }
#pragma unroll
      for (int f = 0; f < NFM; ++f) {
        const int rA = wm0 + f * 16 + a;
        Bf[f] = *(const bf16x8*)((const char*)sA +
                 ((rA * 128 + kh * 64 + g * 16) ^ ((rA & 7) << 4)));
      }
#pragma unroll
      for (int fi = 0; fi < 4; ++fi)
#pragma unroll
        for (int fm = 0; fm < NFM; ++fm)
          acc[fi][fm] = __builtin_amdgcn_mfma_f32_16x16x32_bf16(Af[fi], Bf[fm], acc[fi][fm], 0, 0, 0);
    }
    __syncthreads();
  }

  // acc[fi][fm][r] = D for i = i0+wi0+fi*16+g*4+r, m = m0+wm0+fm*16+a
  if constexpr (EPI == E_SP || EPI == E_SIG) {
    float ssum = 0.f;
#pragma unroll
    for (int fi = 0; fi < 4; ++fi) {
      f32x4 b4 = *(const f32x4*)&bias[i0 + wi0 + fi * 16 + g * 4];
#pragma unroll
      for (int fm = 0; fm < NFM; ++fm)
#pragma unroll
        for (int r = 0; r < 4; ++r) {
          float vv = acc[fi][fm][r] + b4[r];
          if constexpr (EPI == E_SP)
            ssum += fmaxf(vv, 0.f) + log1pf(__expf(-fabsf(vv)));
          else
            ssum += 1.0f / (1.0f + __expf(-vv));
        }
    }
#pragma unroll
    for (int o = 32; o > 0; o >>= 1) ssum += __shfl_xor(ssum, o);
    float* wred = (float*)sT;
    if (l == 0) wred[w] = ssum;
    __syncthreads();
    if (tid == 0) atomicAdd(red, wred[0] + wred[1] + wred[2] + wred[3]);
    return;
  } else {
    float* T = &sT[w][0][0];
    const int iB = i0 + wi0;
    f32x4 b4 = f32x4{0.f, 0.f, 0.f, 0.f};
    if (bias) b4 = *(const f32x4*)&bias[iB + a * 4];
#pragma unroll
    for (int fm = 0; fm < NFM; ++fm) {
#pragma unroll
      for (int fi = 0; fi < 4; ++fi)
        *(f32x4*)&T[a * 68 + fi * 16 + g * 4] = acc[fi][fm];
      asm volatile("s_waitcnt lgkmcnt(0)" ::: "memory");

      if constexpr (EPI != E_MUL) {     // row-major store pass
#pragma unroll
        for (int q = 0; q < 4; ++q) {
          const int ml = wm0 + fm * 16 + q * 4 + g;
          f32x4 v = *(const f32x4*)&T[(q * 4 + g) * 68 + a * 4];
          v += b4;
          if constexpr (EPI == E_F32ADD) {
            const int rr = croff + m0 + ml;
            const int crow = ((rr >> cshift) * cstride) + cbase + (rr & ((1 << cshift) - 1));
            const size_t cb = (size_t)crow * ldc + iB + a * 4;
            v += *(const f32x4*)&faux[cb];
            *(f32x4*)&Cf[cb] = v;
          } else {
            const size_t cb = (size_t)(m0 + ml) * ldc + iB + a * 4;
            if constexpr (EPI == E_BF16) {
              *(bf16x4*)&Cb[cb] = tobf4(v);
            } else if constexpr (EPI == E_GELU) {
              *(bf16x4*)&Cb[cb] = tobf4(gelu4(v));
            } else if constexpr (EPI == E_PAIR) {
              *(bf16x4*)&Cb[cb] = tobf4(v);           // raw h1 (with bias)
              *(bf16x4*)&C2[cb] = tobf4(gelu4(v));    // gelu(h1)
            } else if constexpr (EPI == E_SUB) {
              f32x4 t4 = tof4(*(const bf16x4*)&baux[cb]);
              v = (v - t4) * scale;
              *(bf16x4*)&Cb[cb] = tobf4(v);
            }
          }
        }
      }

      if constexpr (EPI == E_PAIR || EPI == E_SUB || EPI == E_MUL) {
        // transposed store pass: lane l owns output row h = iB + l,
        // reads the slab column-wise (consecutive lanes -> consecutive banks).
        const int mg = m0 + wm0 + fm * 16;
        float tv[16];
#pragma unroll
        for (int j = 0; j < 16; ++j) tv[j] = T[j * 68 + l];
        bf16x8 o0, o1;
        if constexpr (EPI == E_PAIR) {
          float bl = bias[iB + l];
#pragma unroll
          for (int j = 0; j < 16; ++j) {
            float vv = fast_gelu(tv[j] + bl);
            if (j < 8) o0[j] = (bf16)vv; else o1[j - 8] = (bf16)vv;
          }
        } else if constexpr (EPI == E_SUB) {
          float bl = bias[iB + l];
#pragma unroll
          for (int j = 0; j < 16; ++j) {
            float tg = (float)baux[(size_t)(mg + j) * ldc + iB + l];
            float vv = (tv[j] + bl - tg) * scale;
            if (j < 8) o0[j] = (bf16)vv; else o1[j - 8] = (bf16)vv;
          }
        } else {  // E_MUL: da = (od @ W2^T) * gelu'(h1)
#pragma unroll
          for (int j = 0; j < 16; ++j) {
            float h = (float)baux[(size_t)(mg + j) * 1536 + iB + l];
            float vv = tv[j] * fast_gelu_grad(h);
            if (j < 8) o0[j] = (bf16)vv; else o1[j - 8] = (bf16)vv;
          }
        }
        *(bf16x8*)&Ct[(size_t)(iB + l) * ldt + mg] = o0;
        *(bf16x8*)&Ct[(size_t)(iB + l) * ldt + mg + 8] = o1;
      }
    }
  }
}

// ---- MFMA GEMM TN2: G[p][q] += sum_m P[p][m]*Q[q][m]  (m-contig operands) --
// Same staging structure as mm_fwd; fp32 atomicAdd epilogue. grid (pt, qt, z).
__global__ __launch_bounds__(256)
void mm_tn2(const bf16* __restrict__ P, int ldP, const bf16* __restrict__ Q, int ldQ,
            float* __restrict__ G, int ldG, int mlen) {
  __shared__ bf16 sP[128 * 64];
  __shared__ bf16 sQ[128 * 64];
  const int tid = threadIdx.x;
  const int p0 = blockIdx.x * 128, q0 = blockIdx.y * 128;
  const int mb = blockIdx.z * mlen;
  const int l = tid & 63, w = tid >> 6;
  const int a = l & 15, g = l >> 4;
  const int wp0 = (w & 1) * 64, wq0 = (w >> 1) * 64;
  const int lrow = l >> 3;
  const int lcolel = (((l & 7) ^ lrow) << 4) >> 1;

  f32x4 acc[4][4];
#pragma unroll
  for (int i = 0; i < 4; ++i)
#pragma unroll
    for (int j = 0; j < 4; ++j) acc[i][j] = f32x4{0.f, 0.f, 0.f, 0.f};

  for (int m0 = mb; m0 < mb + mlen; m0 += 64) {
#pragma unroll
    for (int t = 0; t < 4; ++t) {
      const int seg = w * 4 + t;
      const int row = seg * 8 + lrow;
      gload16(P + (size_t)(p0 + row) * ldP + m0 + lcolel, (char*)sP + seg * 1024);
      gload16(Q + (size_t)(q0 + row) * ldQ + m0 + lcolel, (char*)sQ + seg * 1024);
    }
    __syncthreads();
#pragma unroll
    for (int kh = 0; kh < 2; ++kh) {
      bf16x8 Pf[4], Qf[4];
#pragma unroll
      for (int f = 0; f < 4; ++f) {
        const int rP = wp0 + f * 16 + a;
        Pf[f] = *(const bf16x8*)((const char*)sP +
                 ((rP * 128 + kh * 64 + g * 16) ^ ((rP & 7) << 4)));
        const int rQ = wq0 + f * 16 + a;
        Qf[f] = *(const bf16x8*)((const char*)sQ +
                 ((rQ * 128 + kh * 64 + g * 16) ^ ((rQ & 7) << 4)));
      }
#pragma unroll
      for (int f1 = 0; f1 < 4; ++f1)
#pragma unroll
        for (int f2 = 0; f2 < 4; ++f2)
          acc[f1][f2] = __builtin_amdgcn_mfma_f32_16x16x32_bf16(Pf[f1], Qf[f2], acc[f1][f2], 0, 0, 0);
    }
    __syncthreads();
  }
#pragma unroll
  for (int f1 = 0; f1 < 4; ++f1)
#pragma unroll
    for (int f2 = 0; f2 < 4; ++f2)
#pragma unroll
      for (int r = 0; r < 4; ++r)
        atomicAdd(&G[(size_t)(p0 + wp0 + f1 * 16 + g * 4 + r) * ldG + q0 + wq0 + f2 * 16 + a],
                  acc[f1][f2][r]);
}

// ---- RoPE in place on q and k (bf16, full chunk) ---------------------------
__global__ __launch_bounds__(256)
void rope_kernel(bf16* __restrict__ q, bf16* __restrict__ k) {
  int idx = blockIdx.x * blockDim.x + threadIdx.x;   // 262144
  int row = idx >> 4, hd = idx & 15;
  int j = row & 2047;
  float pos[3] = { (float)(j >> 8), (float)((j >> 4) & 15), (float)(j & 15) };
  const float freqs[4] = { 1.0f, 0.1f, 0.01f, 0.001f };
  size_t base = (size_t)row * 384 + hd * 24;
  bf16* ptrs[2] = { q + base, k + base };
#pragma unroll
  for (int m2 = 0; m2 < 2; ++m2) {
    bf16* p = ptrs[m2];
#pragma unroll
    for (int s = 0; s < 3; ++s) {
      bf16x8 vv = *(bf16x8*)(p + s * 8);
#pragma unroll
      for (int pr = 0; pr < 4; ++pr) {
        float ang = pos[s] * freqs[pr];
        float si, co;
        sincosf(ang, &si, &co);
        float e0 = (float)vv[2 * pr], e1 = (float)vv[2 * pr + 1];
        vv[2 * pr]     = (bf16)(e0 * co - e1 * si);
        vv[2 * pr + 1] = (bf16)(e0 * si + e1 * co);
      }
      *(bf16x8*)(p + s * 8) = vv;
    }
  }
}

// ---- reductions -------------------------------------------------------------
// row-sum of transposed grids: out[r] += sum_m P[r][m]
__global__ __launch_bounds__(256)
void rowsum(const bf16* __restrict__ P, float* __restrict__ out, int ld, int mlen) {
  int r = blockIdx.x;
  const bf16* p = P + (size_t)r * ld;
  float s = 0.f;
  for (int i = threadIdx.x * 8; i < mlen; i += 256 * 8) {
    bf16x8 v = *(const bf16x8*)&p[i];
#pragma unroll
    for (int e = 0; e < 8; ++e) s += (float)v[e];
  }
  __shared__ float sm[256];
  sm[threadIdx.x] = s; __syncthreads();
  for (int o = 128; o > 0; o >>= 1) {
    if (threadIdx.x < o) sm[threadIdx.x] += sm[threadIdx.x + o];
    __syncthreads();
  }
  if (threadIdx.x == 0) atomicAdd(&out[r], sm[0]);
}

__global__ __launch_bounds__(256)
void sumsq5(const float* __restrict__ G, float* __restrict__ red, int per_i) {
  int i = blockIdx.y;
  const float* base = G + (size_t)i * per_i;
  float s = 0.f;
  for (int idx = blockIdx.x * blockDim.x + threadIdx.x; idx < per_i; idx += gridDim.x * blockDim.x) {
    float v = base[idx]; s += v * v;
  }
  __shared__ float sm[256];
  sm[threadIdx.x] = s; __syncthreads();
  for (int o = 128; o > 0; o >>= 1) {
    if (threadIdx.x < o) sm[threadIdx.x] += sm[threadIdx.x + o];
    __syncthreads();
  }
  if (threadIdx.x == 0) atomicAdd(&red[2 + i], sm[0]);
}

__global__ __launch_bounds__(256)
void update5(float* __restrict__ S, const float* __restrict__ G,
             const float* __restrict__ red, int per_i) {
  int i = blockIdx.y;
  size_t base = (size_t)i * per_i;
  float em = 0.01f * red[0] * INV_CNT;
  float am = red[1] * INV_CNT;
  float norm = sqrtf(red[2 + i]);
  float sc = fminf(1.0f, 1.0f / (norm + 1e-12f));
  float ws_ = 1.0f - am;
  float gs = em * sc;
  for (int idx = blockIdx.x * blockDim.x + threadIdx.x; idx < per_i; idx += gridDim.x * blockDim.x)
    S[base + idx] = ws_ * S[base + idx] - gs * G[base + idx];
}

// ---------------------------------------------------------------------------
extern "C" void kernel_launch(void* const* d_in, const int* in_sizes, int n_in,
                              void* d_out, int out_size, void* d_ws, size_t ws_size,
                              hipStream_t stream) {
  const float* x    = (const float*)d_in[0];
  const float* n1g  = (const float*)d_in[1];
  const float* n1b  = (const float*)d_in[2];
  const float* qW   = (const float*)d_in[3];
  const float* tW1  = (const float*)d_in[4];
  const float* tb1  = (const float*)d_in[5];
  const float* tW2  = (const float*)d_in[6];
  const float* tb2  = (const float*)d_in[7];
  const float* outW = (const float*)d_in[8];
  const float* outb = (const float*)d_in[9];
  const float* n2g  = (const float*)d_in[10];
  const float* n2b  = (const float*)d_in[11];
  const float* cW1  = (const float*)d_in[12];
  const float* cb1  = (const float*)d_in[13];
  const float* cW2  = (const float*)d_in[14];
  const float* cb2  = (const float*)d_in[15];
  float* out = (float*)d_out;

  const size_t W1SZ = 384 * 1536, W2SZ = 1536 * 384;
  const size_t STATE = 5 * W1SZ + 5 * 1536 + 5 * W2SZ + 5 * 384;
  const size_t BF_W = 21 * W1SZ + 2 * 147456;                      // weights bf16
  const size_t CHUNK_BF = 5 * (size_t)16384 * 384;                 // Yc,Kb,Vb,Tt,Kbt
  const size_t FIXEDF = 2 * STATE + 16 + BF_W / 2 + CHUNK_BF / 2;  // f32 units
  // per-MS bf16: H1r,GH1,GH1t,DAt (1536) + OD,ODt,T2 (384) = 7296 -> 3648 f32
  size_t MS = 16384;
  while (MS > 2048 && (FIXEDF + MS * 3648) * 4 > ws_size) MS >>= 1;
  if ((FIXEDF + MS * 3648) * 4 > ws_size) {
    hipMemcpyAsync(d_out, d_in[0], (size_t)25165824 * 4, hipMemcpyDeviceToDevice, stream);
    return;
  }
  const int NS = (int)(16384 / MS);
  const int iMS = (int)MS;

  float* ws = (float*)d_ws;
  size_t off = 0;
  auto alloc = [&](size_t n) { float* p = ws + off; off += n; return p; };
  auto balloc = [&](size_t n) { bf16* p = (bf16*)(ws + off); off += (n + 1) / 2; return p; };
  float* SW1 = alloc(5 * W1SZ);
  float* SB1 = alloc(5 * 1536);
  float* SW2 = alloc(5 * W2SZ);
  float* SB2 = alloc(5 * 384);
  float* G1  = alloc(5 * W1SZ);     // G1..G4 contiguous (single memset)
  float* G2  = alloc(5 * 1536);
  float* G3  = alloc(5 * W2SZ);
  float* G4  = alloc(5 * 384);
  float* RED = alloc(16);
  bf16* Yc   = balloc((size_t)16384 * 384);
  bf16* Kb   = balloc((size_t)16384 * 384);
  bf16* Vb   = balloc((size_t)16384 * 384);
  bf16* Tt   = balloc((size_t)16384 * 384);  // q, then per-memory targets
  bf16* Kbt  = balloc((size_t)16384 * 384);  // [384][16384]
  bf16* sw1t = balloc(5 * W1SZ);   // [1536][384]
  bf16* sw2t = balloc(5 * W2SZ);   // [384][1536]
  bf16* sw2c = balloc(5 * W2SZ);   // [1536][384] straight copy
  bf16* qwt  = balloc(147456);     // [384][384]
  bf16* owt  = balloc(147456);
  bf16* cw1t = balloc(3 * W1SZ);
  bf16* cw2t = balloc(3 * W2SZ);
  bf16* H1r  = balloc(MS * 1536);  // raw h1 [m][1536]
  bf16* GH1  = balloc(MS * 1536);  // gelu(h1) [m][1536]
  bf16* GH1t = balloc(MS * 1536);  // gelu(h1) [1536][m]
  bf16* DAt  = balloc(MS * 1536);  // da [1536][m]
  bf16* OD   = balloc(MS * 384);   // od [m][384]
  bf16* ODt  = balloc(MS * 384);   // od [384][m]
  bf16* T2   = balloc(MS * 384);

  hipMemcpyAsync(SW1, tW1, 5 * W1SZ * 4, hipMemcpyDeviceToDevice, stream);
  hipMemcpyAsync(SB1, tb1, 5 * 1536 * 4, hipMemcpyDeviceToDevice, stream);
  hipMemcpyAsync(SW2, tW2, 5 * W2SZ * 4, hipMemcpyDeviceToDevice, stream);
  hipMemcpyAsync(SB2, tb2, 5 * 384 * 4, hipMemcpyDeviceToDevice, stream);

  trans_w<<<dim3(12, 12), 256, 0, stream>>>(qW, qwt, 384, 384);
  trans_w<<<dim3(12, 12), 256, 0, stream>>>(outW, owt, 384, 384);
  for (int lc = 0; lc < 3; ++lc) {
    trans_w<<<dim3(48, 12), 256, 0, stream>>>(cW1 + lc * W1SZ, cw1t + lc * W1SZ, 384, 1536);
    trans_w<<<dim3(12, 48), 256, 0, stream>>>(cW2 + lc * W2SZ, cw2t + lc * W2SZ, 1536, 384);
  }

  const size_t grads_bytes = STATE * 4;
  const int gm  = (int)(MS / 128);   // BM=128 grid.x
  const int gm2 = (int)(MS / 64);    // BM=64 grid.x
  const int mlen = (iMS >= 2048) ? 2048 : iMS;
  const int zb = iMS / mlen;
  const float SC = 2.0f * INV_CNT;

  for (int c = 0; c < 4; ++c) {
    hipMemsetAsync(G1, 0, grads_bytes, stream);
    hipMemsetAsync(RED, 0, 64, stream);
    for (int i = 0; i < 5; ++i) {
      trans_w<<<dim3(48, 12), 256, 0, stream>>>(SW1 + i * W1SZ, sw1t + i * W1SZ, 384, 1536);
      trans_w<<<dim3(12, 48), 256, 0, stream>>>(SW2 + i * W2SZ, sw2t + i * W2SZ, 1536, 384);
    }
    copy_bf16<<<dim3(2880), 256, 0, stream>>>(SW2, sw2c, (int)(5 * W2SZ));

    ln_kernel<<<dim3(16384), dim3(64), 0, stream>>>(x, n1g, n1b, Yc, 11, c * 2048, 8192);

    // ---- gen: k, v, eta(mean), alpha(mean) ----
    for (int i = 0; i < 4; ++i) {
      for (int s = 0; s < NS; ++s) {
        const bf16* Ys = Yc + (size_t)s * MS * 384;
        mm_fwd<E_GELU, 128><<<dim3(gm, 12), 256, 0, stream>>>(Ys, sw1t + i * W1SZ,
            SB1 + i * 1536, nullptr, nullptr, nullptr, GH1, nullptr, nullptr, nullptr,
            384, 1536, 0, 0.f, 0, 30, 0, 0);
        if (i == 0)
          mm_fwd<E_BF16, 64><<<dim3(gm2, 3), 256, 0, stream>>>(GH1, sw2t + i * W2SZ,
              SB2 + i * 384, nullptr, nullptr, nullptr, Kb + (size_t)s * MS * 384,
              nullptr, nullptr, nullptr, 1536, 384, 0, 0.f, 0, 30, 0, 0);
        else if (i == 1)
          mm_fwd<E_BF16, 64><<<dim3(gm2, 3), 256, 0, stream>>>(GH1, sw2t + i * W2SZ,
              SB2 + i * 384, nullptr, nullptr, nullptr, Vb + (size_t)s * MS * 384,
              nullptr, nullptr, nullptr, 1536, 384, 0, 0.f, 0, 30, 0, 0);
        else if (i == 2)
          mm_fwd<E_SP, 64><<<dim3(gm2, 3), 256, 0, stream>>>(GH1, sw2t + i * W2SZ,
              SB2 + i * 384, nullptr, nullptr, RED + 0, nullptr, nullptr, nullptr, nullptr,
              1536, 384, 0, 0.f, 0, 30, 0, 0);
        else
          mm_fwd<E_SIG, 64><<<dim3(gm2, 3), 256, 0, stream>>>(GH1, sw2t + i * W2SZ,
              SB2 + i * 384, nullptr, nullptr, RED + 1, nullptr, nullptr, nullptr, nullptr,
              1536, 384, 0, 0.f, 0, 30, 0, 0);
      }
    }

    // ---- q = yc @ qW (into Tt), rope(q, k), Kbt = Kb^T ----
    for (int s = 0; s < NS; ++s)
      mm_fwd<E_BF16, 64><<<dim3(gm2, 3), 256, 0, stream>>>(Yc + (size_t)s * MS * 384, qwt,
          nullptr, nullptr, nullptr, nullptr, Tt + (size_t)s * MS * 384, nullptr, nullptr,
          nullptr, 384, 384, 0, 0.f, 0, 30, 0, 0);
    rope_kernel<<<dim3(1024), 256, 0, stream>>>(Tt, Kb);
    tr_bf<<<dim3(512, 12), 256, 0, stream>>>(Kb, Kbt, 16384, 384);

    // ---- out = mlp4(q) -> proj + residual scatter into d_out ----
    for (int s = 0; s < NS; ++s) {
      mm_fwd<E_GELU, 128><<<dim3(gm, 12), 256, 0, stream>>>(Tt + (size_t)s * MS * 384,
          sw1t + 4 * W1SZ, SB1 + 4 * 1536, nullptr, nullptr, nullptr, GH1, nullptr, nullptr,
          nullptr, 384, 1536, 0, 0.f, 0, 30, 0, 0);
      mm_fwd<E_BF16, 64><<<dim3(gm2, 3), 256, 0, stream>>>(GH1, sw2t + 4 * W2SZ,
          SB2 + 4 * 384, nullptr, nullptr, nullptr, T2, nullptr, nullptr, nullptr,
          1536, 384, 0, 0.f, 0, 30, 0, 0);
      mm_fwd<E_F32ADD, 64><<<dim3(gm2, 3), 256, 0, stream>>>(T2, owt, outb,
          nullptr, x, nullptr, nullptr, nullptr, nullptr, out,
          384, 384, 0, 0.f, (int)(s * MS), 11, c * 2048, 8192);
    }

    // ---- per-memory: target then grads ----
    for (int i = 0; i < 5; ++i) {
      if (i < 4) {
        for (int s = 0; s < NS; ++s) {
          mm_fwd<E_GELU, 128><<<dim3(gm, 12), 256, 0, stream>>>(Vb + (size_t)s * MS * 384,
              sw1t + i * W1SZ, SB1 + i * 1536, nullptr, nullptr, nullptr, GH1, nullptr,
              nullptr, nullptr, 384, 1536, 0, 0.f, 0, 30, 0, 0);
          mm_fwd<E_BF16, 64><<<dim3(gm2, 3), 256, 0, stream>>>(GH1, sw2t + i * W2SZ,
              SB2 + i * 384, nullptr, nullptr, nullptr, Tt + (size_t)s * MS * 384,
              nullptr, nullptr, nullptr, 1536, 384, 0, 0.f, 0, 30, 0, 0);
        }
      }
      for (int s = 0; s < NS; ++s) {
        const bf16* Ks = Kb + (size_t)s * MS * 384;
        const bf16* tg = ((i < 4) ? Tt : Vb) + (size_t)s * MS * 384;
        // k-forward: H1r rm, GH1 rm, GH1t transposed
        mm_fwd<E_PAIR, 128><<<dim3(gm, 12), 256, 0, stream>>>(Ks, sw1t + i * W1SZ,
            SB1 + i * 1536, nullptr, nullptr, nullptr, H1r, GH1, GH1t, nullptr,
            384, 1536, iMS, 0.f, 0, 30, 0, 0);
        // od = (pred - tgt)*sc: OD rm + ODt
        mm_fwd<E_SUB, 64><<<dim3(gm2, 3), 256, 0, stream>>>(GH1, sw2t + i * W2SZ,
            SB2 + i * 384, tg, nullptr, nullptr, OD, nullptr, ODt, nullptr,
            1536, 384, iMS, SC, 0, 30, 0, 0);
        rowsum<<<dim3(384), 256, 0, stream>>>(ODt, G4 + i * 384, iMS, iMS);
        mm_tn2<<<dim3(12, 3, zb), 256, 0, stream>>>(GH1t, iMS, ODt, iMS,
            G3 + i * W2SZ, 384, mlen);
        // da = (od @ W2^T) * gelu'(h1): DAt only
        mm_fwd<E_MUL, 128><<<dim3(gm, 12), 256, 0, stream>>>(OD, sw2c + i * W2SZ,
            nullptr, H1r, nullptr, nullptr, nullptr, nullptr, DAt, nullptr,
            384, 1536, iMS, 0.f, 0, 30, 0, 0);
        rowsum<<<dim3(1536), 256, 0, stream>>>(DAt, G2 + i * 1536, iMS, iMS);
        mm_tn2<<<dim3(3, 12, zb), 256, 0, stream>>>(Kbt + (size_t)s * MS, 16384, DAt, iMS,
            G1 + i * W1SZ, 1536, mlen);
      }
    }

    // ---- norms + state update ----
    sumsq5<<<dim3(256, 5), 256, 0, stream>>>(G1, RED, (int)W1SZ);
    sumsq5<<<dim3(2, 5), 256, 0, stream>>>(G2, RED, 1536);
    sumsq5<<<dim3(256, 5), 256, 0, stream>>>(G3, RED, (int)W2SZ);
    sumsq5<<<dim3(2, 5), 256, 0, stream>>>(G4, RED, 384);
    update5<<<dim3(512, 5), 256, 0, stream>>>(SW1, G1, RED, (int)W1SZ);
    update5<<<dim3(4, 5), 256, 0, stream>>>(SB1, G2, RED, 1536);
    update5<<<dim3(512, 5), 256, 0, stream>>>(SW2, G3, RED, (int)W2SZ);
    update5<<<dim3(4, 5), 256, 0, stream>>>(SB2, G4, RED, 384);
  }

  // ---- norm2 + 3 CMS MLP layers (+ fused final residual), per MS slice ----
  const int NCS = (int)(65536 / MS);
  for (int s2 = 0; s2 < NCS; ++s2) {
    float* outp = out + (size_t)s2 * MS * 384;
    ln_kernel<<<dim3(iMS), dim3(64), 0, stream>>>(out, n2g, n2b, OD, 30, (int)(s2 * MS), 0);
    bf16* hc = OD; bf16* hn = T2;
    for (int lc = 0; lc < 3; ++lc) {
      mm_fwd<E_GELU, 128><<<dim3(gm, 12), 256, 0, stream>>>(hc, cw1t + lc * W1SZ,
          cb1 + lc * 1536, nullptr, nullptr, nullptr, GH1, nullptr, nullptr, nullptr,
          384, 1536, 0, 0.f, 0, 30, 0, 0);
      if (lc < 2) {
        mm_fwd<E_BF16, 64><<<dim3(gm2, 3), 256, 0, stream>>>(GH1, cw2t + lc * W2SZ,
            cb2 + lc * 384, nullptr, nullptr, nullptr, hn, nullptr, nullptr, nullptr,
            1536, 384, 0, 0.f, 0, 30, 0, 0);
        bf16* t = hc; hc = hn; hn = t;
      } else {
        mm_fwd<E_F32ADD, 64><<<dim3(gm2, 3), 256, 0, stream>>>(GH1, cw2t + lc * W2SZ,
            cb2 + lc * 384, nullptr, outp, nullptr, nullptr, nullptr, nullptr, outp,
            1536, 384, 0, 0.f, 0, 30, 0, 0);
      }
    }
  }
}